// Round 1
// baseline (5890.800 us; speedup 1.0000x reference)
//
#include <hip/hip_runtime.h>
#include <math.h>

#define EPS_LN 1e-5f

// Monotone float -> uint key: preserves ordering, 0 is below every real float's key,
// so memset(0) == "empty segment" (exactly the counts>0 semantics in the reference).
__device__ __forceinline__ unsigned ordkey(float f) {
    unsigned u = __float_as_uint(f);
    return (u & 0x80000000u) ? ~u : (u | 0x80000000u);
}
__device__ __forceinline__ float orddecode(unsigned o) {
    unsigned u = (o & 0x80000000u) ? (o & 0x7FFFFFFFu) : ~o;
    return __uint_as_float(u);
}

// ---------------------------------------------------------------------------
// Stage 2: per-point MLP1 (Linear(3,64) -> LN -> ReLU -> Linear(64,64))
// fused with scatter-max via u32 ordered-key atomics.
// One thread per point; W1/b1/g1/be1/W2/b2 staged in LDS (~18 KB).
// ---------------------------------------------------------------------------
__global__ __launch_bounds__(256) void mlp1_scatter_kernel(
    const float* __restrict__ x, const int* __restrict__ bidx,
    const float* __restrict__ W1, const float* __restrict__ b1,
    const float* __restrict__ g1, const float* __restrict__ be1,
    const float* __restrict__ W2, const float* __restrict__ b2,
    unsigned* __restrict__ seg_ord, int P)
{
    __shared__ float sW1[3 * 64];
    __shared__ float sb1[64], sg1[64], sbe1[64], sb2[64];
    __shared__ float sW2[64 * 64];

    const int tid = threadIdx.x;
    for (int i = tid; i < 3 * 64; i += 256) sW1[i] = W1[i];
    if (tid < 64) {
        sb1[tid]  = b1[tid];
        sg1[tid]  = g1[tid];
        sbe1[tid] = be1[tid];
        sb2[tid]  = b2[tid];
    }
    for (int i = tid; i < 64 * 64; i += 256) sW2[i] = W2[i];
    __syncthreads();

    const int p = blockIdx.x * 256 + tid;
    if (p >= P) return;

    const float x0 = x[3 * p + 0];
    const float x1 = x[3 * p + 1];
    const float x2 = x[3 * p + 2];

    // y = x @ W1 + b1  (64 outputs), keep in registers
    float a[64];
    float sum = 0.f;
#pragma unroll
    for (int j = 0; j < 64; j++) {
        float y = fmaf(x0, sW1[j], fmaf(x1, sW1[64 + j], fmaf(x2, sW1[128 + j], sb1[j])));
        a[j] = y;
        sum += y;
    }
    const float mu = sum * (1.f / 64.f);
    float vs = 0.f;
#pragma unroll
    for (int j = 0; j < 64; j++) {
        float d = a[j] - mu;
        vs = fmaf(d, d, vs);
    }
    const float rs = rsqrtf(vs * (1.f / 64.f) + EPS_LN);
#pragma unroll
    for (int j = 0; j < 64; j++) {
        float v = fmaf((a[j] - mu) * rs, sg1[j], sbe1[j]);
        a[j] = v > 0.f ? v : 0.f;   // ReLU
    }

    const int node = bidx[p];
    unsigned* segp = seg_ord + (size_t)node * 64;

    // z = a @ W2 + b2, j tiled in halves of 32 to bound register pressure.
#pragma unroll
    for (int jt = 0; jt < 64; jt += 32) {
        float4 acc[8];
#pragma unroll
        for (int q = 0; q < 8; q++) acc[q] = *(const float4*)&sb2[jt + 4 * q];
#pragma unroll 8
        for (int k = 0; k < 64; k++) {
            const float ak = a[k];
            const float4* w = (const float4*)&sW2[k * 64 + jt];  // wave-uniform broadcast
#pragma unroll
            for (int q = 0; q < 8; q++) {
                float4 wv = w[q];
                acc[q].x = fmaf(ak, wv.x, acc[q].x);
                acc[q].y = fmaf(ak, wv.y, acc[q].y);
                acc[q].z = fmaf(ak, wv.z, acc[q].z);
                acc[q].w = fmaf(ak, wv.w, acc[q].w);
            }
        }
#pragma unroll
        for (int q = 0; q < 8; q++) {
            atomicMax(&segp[jt + 4 * q + 0], ordkey(acc[q].x));
            atomicMax(&segp[jt + 4 * q + 1], ordkey(acc[q].y));
            atomicMax(&segp[jt + 4 * q + 2], ordkey(acc[q].z));
            atomicMax(&segp[jt + 4 * q + 3], ordkey(acc[q].w));
        }
    }
}

// ---------------------------------------------------------------------------
// Stage 3: decode segment maxima (empty -> 0) then
// MLP2: Linear(64,128) -> LN -> ReLU -> Linear(128,128), fp32.
// 256 threads = 2 nodes x 128 "output-dim" threads; W3/W4 in LDS (96 KB).
// ---------------------------------------------------------------------------
__global__ __launch_bounds__(256) void mlp2_kernel(
    const unsigned* __restrict__ seg_ord,
    const float* __restrict__ W3, const float* __restrict__ b3,
    const float* __restrict__ g2, const float* __restrict__ be2,
    const float* __restrict__ W4, const float* __restrict__ b4,
    float* __restrict__ out, int N)
{
    __shared__ float sW3[64 * 128];   // 32 KB
    __shared__ float sW4[128 * 128];  // 64 KB
    __shared__ float sb3[128], sg2[128], sbe2[128], sb4[128];
    __shared__ float s_s[2][64];
    __shared__ float s_u[2][128];
    __shared__ float red[2][2][2];    // [half][wave-in-half][{sum,sumsq}]

    const int tid = threadIdx.x;
    for (int i = tid; i < 64 * 128; i += 256) sW3[i] = W3[i];
    for (int i = tid; i < 128 * 128; i += 256) sW4[i] = W4[i];
    if (tid < 128) {
        sb3[tid]  = b3[tid];
        sg2[tid]  = g2[tid];
        sbe2[tid] = be2[tid];
        sb4[tid]  = b4[tid];
    }
    __syncthreads();

    const int half = tid >> 7;          // node within pair
    const int j    = tid & 127;         // output dim
    const int waveInHalf = (tid >> 6) & 1;
    const int lane = tid & 63;

    for (int n0 = blockIdx.x * 2; n0 < N; n0 += gridDim.x * 2) {
        const int node = n0 + half;

        if (j < 64) {
            unsigned o = seg_ord[(size_t)node * 64 + j];
            s_s[half][j] = (o == 0u) ? 0.f : orddecode(o);
        }
        __syncthreads();

        // t = s @ W3 + b3
        float t = sb3[j];
#pragma unroll 8
        for (int k = 0; k < 64; k++) t = fmaf(s_s[half][k], sW3[k * 128 + j], t);

        // LN over the 128 dims of this half (2 waves)
        float s1 = t, s2 = t * t;
#pragma unroll
        for (int off = 32; off > 0; off >>= 1) {
            s1 += __shfl_down(s1, off);
            s2 += __shfl_down(s2, off);
        }
        if (lane == 0) { red[half][waveInHalf][0] = s1; red[half][waveInHalf][1] = s2; }
        __syncthreads();

        const float sumt  = red[half][0][0] + red[half][1][0];
        const float sumt2 = red[half][0][1] + red[half][1][1];
        const float mu  = sumt * (1.f / 128.f);
        const float var = sumt2 * (1.f / 128.f) - mu * mu;
        const float rsd = rsqrtf(var + EPS_LN);
        float u = fmaf((t - mu) * rsd, sg2[j], sbe2[j]);
        u = u > 0.f ? u : 0.f;
        s_u[half][j] = u;
        __syncthreads();

        // o = u @ W4 + b4
        float o = sb4[j];
#pragma unroll 8
        for (int k = 0; k < 128; k++) o = fmaf(s_u[half][k], sW4[k * 128 + j], o);
        out[(size_t)node * 128 + j] = o;
        __syncthreads();   // protect s_s/red for next iteration
    }
}

extern "C" void kernel_launch(void* const* d_in, const int* in_sizes, int n_in,
                              void* d_out, int out_size, void* d_ws, size_t ws_size,
                              hipStream_t stream) {
    const float* x    = (const float*)d_in[0];
    const int*   bidx = (const int*)d_in[1];   // JAX w/o x64 => int32
    // d_in[2] = num_nodes scalar (derive N from out_size instead)
    const float* W1  = (const float*)d_in[3];
    const float* b1  = (const float*)d_in[4];
    const float* g1  = (const float*)d_in[5];
    const float* be1 = (const float*)d_in[6];
    const float* W2  = (const float*)d_in[7];
    const float* b2  = (const float*)d_in[8];
    const float* W3  = (const float*)d_in[9];
    const float* b3  = (const float*)d_in[10];
    const float* g2  = (const float*)d_in[11];
    const float* be2 = (const float*)d_in[12];
    const float* W4  = (const float*)d_in[13];
    const float* b4  = (const float*)d_in[14];

    const int P = in_sizes[0] / 3;
    const int N = out_size / 128;

    unsigned* seg_ord = (unsigned*)d_ws;   // N*64 u32 = 16 MiB

    hipMemsetAsync(d_ws, 0, (size_t)N * 64 * sizeof(unsigned), stream);

    const int grid1 = (P + 255) / 256;
    mlp1_scatter_kernel<<<grid1, 256, 0, stream>>>(
        x, bidx, W1, b1, g1, be1, W2, b2, seg_ord, P);

    mlp2_kernel<<<256, 256, 0, stream>>>(
        seg_ord, W3, b3, g2, be2, W4, b4, (float*)d_out, N);
}

// Round 2
// 2942.957 us; speedup vs baseline: 2.0017x; 2.0017x over previous
//
#include <hip/hip_runtime.h>
#include <math.h>

#define EPS_LN 1e-5f

// ---------------------------------------------------------------------------
// K1: histogram of batch_idx -> counts[N]
// ---------------------------------------------------------------------------
__global__ __launch_bounds__(256) void hist_kernel(const int* __restrict__ bidx,
                                                   unsigned* __restrict__ counts, int P) {
    int p = blockIdx.x * 256 + threadIdx.x;
    if (p < P) atomicAdd(&counts[bidx[p]], 1u);
}

// ---------------------------------------------------------------------------
// K2: exclusive scan counts -> offsets[N+1]; cursor[N] = offsets[0..N-1]
// Single block, 1024 threads, 64 elements/thread. Requires N <= 65536.
// ---------------------------------------------------------------------------
__global__ __launch_bounds__(1024) void scan_kernel(const unsigned* __restrict__ counts,
                                                    unsigned* __restrict__ offsets,
                                                    unsigned* __restrict__ cursor, int N) {
    __shared__ unsigned waveTot[16];
    const int t = threadIdx.x;
    const int base = t * 64;
    unsigned local[64];
    unsigned s = 0;
    for (int i = 0; i < 64; i++) {
        int idx = base + i;
        unsigned c = (idx < N) ? counts[idx] : 0u;
        local[i] = s;
        s += c;
    }
    // inclusive wave scan of chunk totals
    unsigned v = s;
    const int lane = t & 63;
    for (int off = 1; off < 64; off <<= 1) {
        unsigned u = __shfl_up(v, off);
        if (lane >= off) v += u;
    }
    if (lane == 63) waveTot[t >> 6] = v;
    __syncthreads();
    if (t == 0) {
        unsigned acc = 0;
        for (int w = 0; w < 16; w++) { unsigned tmp = waveTot[w]; waveTot[w] = acc; acc += tmp; }
    }
    __syncthreads();
    const unsigned chunkBase = waveTot[t >> 6] + (v - s);   // exclusive base of this chunk
    for (int i = 0; i < 64; i++) {
        int idx = base + i;
        if (idx < N) {
            unsigned o = chunkBase + local[i];
            offsets[idx] = o;
            cursor[idx]  = o;
        }
    }
    if (t == 1023) offsets[N] = chunkBase + s;   // = total P
}

// ---------------------------------------------------------------------------
// K3: scatter point indices into node buckets
// ---------------------------------------------------------------------------
__global__ __launch_bounds__(256) void scatter_kernel(const int* __restrict__ bidx,
                                                      unsigned* __restrict__ cursor,
                                                      unsigned* __restrict__ bucket, int P) {
    int p = blockIdx.x * 256 + threadIdx.x;
    if (p < P) {
        unsigned pos = atomicAdd(&cursor[bidx[p]], 1u);
        bucket[pos] = (unsigned)p;
    }
}

// ---------------------------------------------------------------------------
// K4: per-node fused MLP1 + max pool. 2 threads per node (even/odd points),
// combined via shfl_xor — zero global atomics, max kept in registers.
// MLP1 = Linear(3,64) -> LN -> ReLU -> Linear(64,64), all fp32 registers;
// W2 read as wave-uniform float4 LDS broadcasts.
// ---------------------------------------------------------------------------
__global__ __launch_bounds__(256) void pool_kernel(
    const float* __restrict__ x, const unsigned* __restrict__ bucket,
    const unsigned* __restrict__ offsets,
    const float* __restrict__ W1, const float* __restrict__ b1,
    const float* __restrict__ g1, const float* __restrict__ be1,
    const float* __restrict__ W2, const float* __restrict__ b2,
    float* __restrict__ seg, int N)
{
    __shared__ float sW1[192], sb1[64], sg1[64], sbe1[64], sb2[64];
    __shared__ float sW2[4096];
    const int tid = threadIdx.x;
    for (int i = tid; i < 192; i += 256) sW1[i] = W1[i];
    if (tid < 64) { sb1[tid] = b1[tid]; sg1[tid] = g1[tid]; sbe1[tid] = be1[tid]; sb2[tid] = b2[tid]; }
    for (int i = tid; i < 4096; i += 256) sW2[i] = W2[i];
    __syncthreads();

    const int gtid = blockIdx.x * 256 + tid;
    if (gtid >= 2 * N) return;
    const int node  = gtid >> 1;
    const int phase = gtid & 1;

    const unsigned start = offsets[node], end = offsets[node + 1];

    float smax[64];
#pragma unroll
    for (int j = 0; j < 64; j++) smax[j] = -3.4e38f;

    for (unsigned it = start + phase; it < end; it += 2) {
        const unsigned p = bucket[it];
        const float x0 = x[3 * p + 0];
        const float x1 = x[3 * p + 1];
        const float x2 = x[3 * p + 2];

        float a[64];
        float sum = 0.f;
#pragma unroll
        for (int j = 0; j < 64; j++) {
            float y = fmaf(x0, sW1[j], fmaf(x1, sW1[64 + j], fmaf(x2, sW1[128 + j], sb1[j])));
            a[j] = y;
            sum += y;
        }
        const float mu = sum * (1.f / 64.f);
        float vs = 0.f;
#pragma unroll
        for (int j = 0; j < 64; j++) { float d = a[j] - mu; vs = fmaf(d, d, vs); }
        const float rs = rsqrtf(vs * (1.f / 64.f) + EPS_LN);
#pragma unroll
        for (int j = 0; j < 64; j++) {
            float v = fmaf((a[j] - mu) * rs, sg1[j], sbe1[j]);
            a[j] = v > 0.f ? v : 0.f;
        }

#pragma unroll
        for (int jt = 0; jt < 64; jt += 32) {
            float4 acc[8];
#pragma unroll
            for (int q = 0; q < 8; q++) acc[q] = *(const float4*)&sb2[jt + 4 * q];
#pragma unroll 8
            for (int k = 0; k < 64; k++) {
                const float ak = a[k];
                const float4* w = (const float4*)&sW2[k * 64 + jt];  // wave-uniform -> LDS broadcast
#pragma unroll
                for (int q = 0; q < 8; q++) {
                    float4 wv = w[q];
                    acc[q].x = fmaf(ak, wv.x, acc[q].x);
                    acc[q].y = fmaf(ak, wv.y, acc[q].y);
                    acc[q].z = fmaf(ak, wv.z, acc[q].z);
                    acc[q].w = fmaf(ak, wv.w, acc[q].w);
                }
            }
#pragma unroll
            for (int q = 0; q < 8; q++) {
                smax[jt + 4 * q + 0] = fmaxf(smax[jt + 4 * q + 0], acc[q].x);
                smax[jt + 4 * q + 1] = fmaxf(smax[jt + 4 * q + 1], acc[q].y);
                smax[jt + 4 * q + 2] = fmaxf(smax[jt + 4 * q + 2], acc[q].z);
                smax[jt + 4 * q + 3] = fmaxf(smax[jt + 4 * q + 3], acc[q].w);
            }
        }
    }

    // combine even/odd phases: partner is the adjacent lane in the same wave
    const bool empty = (end == start);
    float out_j;
    float* o = seg + (size_t)node * 64;
#pragma unroll
    for (int j = 0; j < 64; j++) {
        float other = __shfl_xor(smax[j], 1);
        out_j = fmaxf(smax[j], other);
        if (phase == 0) o[j] = empty ? 0.f : out_j;
    }
}

// ---------------------------------------------------------------------------
// K5: MLP2: Linear(64,128) -> LN -> ReLU -> Linear(128,128), fp32.
// 256 threads = 2 nodes x 128 output-dim threads; W3/W4 in LDS (96 KB).
// ---------------------------------------------------------------------------
__global__ __launch_bounds__(256) void mlp2_kernel(
    const float* __restrict__ seg,
    const float* __restrict__ W3, const float* __restrict__ b3,
    const float* __restrict__ g2, const float* __restrict__ be2,
    const float* __restrict__ W4, const float* __restrict__ b4,
    float* __restrict__ out, int N)
{
    __shared__ float sW3[64 * 128];   // 32 KB
    __shared__ float sW4[128 * 128];  // 64 KB
    __shared__ float sb3[128], sg2[128], sbe2[128], sb4[128];
    __shared__ float s_s[2][64];
    __shared__ float s_u[2][128];
    __shared__ float red[2][2][2];

    const int tid = threadIdx.x;
    for (int i = tid; i < 64 * 128; i += 256) sW3[i] = W3[i];
    for (int i = tid; i < 128 * 128; i += 256) sW4[i] = W4[i];
    if (tid < 128) {
        sb3[tid]  = b3[tid];
        sg2[tid]  = g2[tid];
        sbe2[tid] = be2[tid];
        sb4[tid]  = b4[tid];
    }
    __syncthreads();

    const int half = tid >> 7;
    const int j    = tid & 127;
    const int waveInHalf = (tid >> 6) & 1;
    const int lane = tid & 63;

    for (int n0 = blockIdx.x * 2; n0 < N; n0 += gridDim.x * 2) {
        const int node = n0 + half;

        if (j < 64) s_s[half][j] = seg[(size_t)node * 64 + j];
        __syncthreads();

        float t = sb3[j];
#pragma unroll 8
        for (int k = 0; k < 64; k++) t = fmaf(s_s[half][k], sW3[k * 128 + j], t);

        float s1 = t, s2 = t * t;
#pragma unroll
        for (int off = 32; off > 0; off >>= 1) {
            s1 += __shfl_down(s1, off);
            s2 += __shfl_down(s2, off);
        }
        if (lane == 0) { red[half][waveInHalf][0] = s1; red[half][waveInHalf][1] = s2; }
        __syncthreads();

        const float sumt  = red[half][0][0] + red[half][1][0];
        const float sumt2 = red[half][0][1] + red[half][1][1];
        const float mu  = sumt * (1.f / 128.f);
        const float var = sumt2 * (1.f / 128.f) - mu * mu;
        const float rsd = rsqrtf(var + EPS_LN);
        float u = fmaf((t - mu) * rsd, sg2[j], sbe2[j]);
        u = u > 0.f ? u : 0.f;
        s_u[half][j] = u;
        __syncthreads();

        float o = sb4[j];
#pragma unroll 8
        for (int k = 0; k < 128; k++) o = fmaf(s_u[half][k], sW4[k * 128 + j], o);
        out[(size_t)node * 128 + j] = o;
        __syncthreads();
    }
}

extern "C" void kernel_launch(void* const* d_in, const int* in_sizes, int n_in,
                              void* d_out, int out_size, void* d_ws, size_t ws_size,
                              hipStream_t stream) {
    const float* x    = (const float*)d_in[0];
    const int*   bidx = (const int*)d_in[1];
    const float* W1  = (const float*)d_in[3];
    const float* b1  = (const float*)d_in[4];
    const float* g1  = (const float*)d_in[5];
    const float* be1 = (const float*)d_in[6];
    const float* W2  = (const float*)d_in[7];
    const float* b2  = (const float*)d_in[8];
    const float* W3  = (const float*)d_in[9];
    const float* b3  = (const float*)d_in[10];
    const float* g2  = (const float*)d_in[11];
    const float* be2 = (const float*)d_in[12];
    const float* W4  = (const float*)d_in[13];
    const float* b4  = (const float*)d_in[14];

    const int P = in_sizes[0] / 3;
    const int N = out_size / 128;

    // workspace carve (all 256B aligned)
    uintptr_t w = (uintptr_t)d_ws;
    auto align = [](uintptr_t v) { return (v + 255) & ~(uintptr_t)255; };
    unsigned* counts  = (unsigned*)align(w);                 w = (uintptr_t)(counts  + N);
    unsigned* offsets = (unsigned*)align(w);                 w = (uintptr_t)(offsets + N + 1);
    unsigned* cursor  = (unsigned*)align(w);                 w = (uintptr_t)(cursor  + N);
    unsigned* bucket  = (unsigned*)align(w);                 w = (uintptr_t)(bucket  + P);
    float*    seg     = (float*)align(w);

    hipMemsetAsync(counts, 0, (size_t)N * sizeof(unsigned), stream);

    const int gridP = (P + 255) / 256;
    hist_kernel<<<gridP, 256, 0, stream>>>(bidx, counts, P);
    scan_kernel<<<1, 1024, 0, stream>>>(counts, offsets, cursor, N);
    scatter_kernel<<<gridP, 256, 0, stream>>>(bidx, cursor, bucket, P);

    const int gridPool = (2 * N + 255) / 256;
    pool_kernel<<<gridPool, 256, 0, stream>>>(
        x, bucket, offsets, W1, b1, g1, be1, W2, b2, seg, N);

    mlp2_kernel<<<256, 256, 0, stream>>>(
        seg, W3, b3, g2, be2, W4, b4, (float*)d_out, N);
}

// Round 3
// 1291.731 us; speedup vs baseline: 4.5604x; 2.2783x over previous
//
#include <hip/hip_runtime.h>
#include <hip/hip_bf16.h>
#include <math.h>

#define EPS_LN 1e-5f

// Monotone float->uint key; 0 encodes "never written" (= empty segment -> 0.0 later).
__device__ __forceinline__ unsigned ordkey(float f) {
    unsigned u = __float_as_uint(f);
    return (u & 0x80000000u) ? ~u : (u | 0x80000000u);
}
__device__ __forceinline__ float orddecode(unsigned o) {
    unsigned u = (o & 0x80000000u) ? (o & 0x7FFFFFFFu) : ~o;
    return __uint_as_float(u);
}

// ---------------------------------------------------------------------------
// K1: histogram of batch_idx -> counts[N]
// ---------------------------------------------------------------------------
__global__ __launch_bounds__(256) void hist_kernel(const int* __restrict__ bidx,
                                                   unsigned* __restrict__ counts, int P) {
    int p = blockIdx.x * 256 + threadIdx.x;
    if (p < P) atomicAdd(&counts[bidx[p]], 1u);
}

// ---------------------------------------------------------------------------
// K2: exclusive scan counts -> offsets[N+1]; cursor[N] = offsets[0..N-1]
// Single block, 1024 threads, 64 elements/thread. Requires N <= 65536.
// ---------------------------------------------------------------------------
__global__ __launch_bounds__(1024) void scan_kernel(const unsigned* __restrict__ counts,
                                                    unsigned* __restrict__ offsets,
                                                    unsigned* __restrict__ cursor, int N) {
    __shared__ unsigned waveTot[16];
    const int t = threadIdx.x;
    const int base = t * 64;
    unsigned local[64];
    unsigned s = 0;
    for (int i = 0; i < 64; i++) {
        int idx = base + i;
        unsigned c = (idx < N) ? counts[idx] : 0u;
        local[i] = s;
        s += c;
    }
    unsigned v = s;
    const int lane = t & 63;
    for (int off = 1; off < 64; off <<= 1) {
        unsigned u = __shfl_up(v, off);
        if (lane >= off) v += u;
    }
    if (lane == 63) waveTot[t >> 6] = v;
    __syncthreads();
    if (t == 0) {
        unsigned acc = 0;
        for (int w = 0; w < 16; w++) { unsigned tmp = waveTot[w]; waveTot[w] = acc; acc += tmp; }
    }
    __syncthreads();
    const unsigned chunkBase = waveTot[t >> 6] + (v - s);
    for (int i = 0; i < 64; i++) {
        int idx = base + i;
        if (idx < N) {
            unsigned o = chunkBase + local[i];
            offsets[idx] = o;
            cursor[idx]  = o;
        }
    }
    if (t == 1023) offsets[N] = chunkBase + s;
}

// ---------------------------------------------------------------------------
// K3: scatter (point, node) records into node buckets
// ---------------------------------------------------------------------------
__global__ __launch_bounds__(256) void scatter_kernel(const int* __restrict__ bidx,
                                                      unsigned* __restrict__ cursor,
                                                      uint2* __restrict__ bucket2, int P) {
    int p = blockIdx.x * 256 + threadIdx.x;
    if (p < P) {
        int n = bidx[p];
        unsigned pos = atomicAdd(&cursor[n], 1u);
        bucket2[pos] = make_uint2((unsigned)p, (unsigned)n);
    }
}

// ---------------------------------------------------------------------------
// K4: fused MLP1 + chunk-segmented max pool.
// Block = 256 contiguous bucket positions (node-sorted). Thread-per-point
// MLP1 with on-the-fly LN (no a[64] array), h -> LDS as bf16 (padded stride),
// then block-level segmented max: interior nodes plain-store ordkey, boundary
// nodes (<=2 per block) atomicMax. Empty nodes stay memset(0) -> decode 0.
// ---------------------------------------------------------------------------
__global__ __launch_bounds__(256, 3) void fused_mlp1_pool_kernel(
    const float* __restrict__ x, const uint2* __restrict__ bucket2,
    const unsigned* __restrict__ offsets,
    const float* __restrict__ W1, const float* __restrict__ b1,
    const float* __restrict__ g1, const float* __restrict__ be1,
    const float* __restrict__ W2, const float* __restrict__ b2,
    unsigned* __restrict__ segord, int P)
{
    __shared__ float4 sW1p[64];                 // (w0,w1,w2,b1) per channel
    __shared__ float sg1[64], sbe1[64], sb2[64];
    __shared__ float sW2[4096];                 // 16 KB
    __shared__ __hip_bfloat162 sh[256 * 33];    // 256 rows x 32 bf162 (+1 pad) = 33.8 KB
    __shared__ unsigned snode[256];

    const int tid = threadIdx.x;
    if (tid < 64) {
        sW1p[tid] = make_float4(W1[tid], W1[64 + tid], W1[128 + tid], b1[tid]);
        sg1[tid]  = g1[tid];
        sbe1[tid] = be1[tid];
        sb2[tid]  = b2[tid];
    }
    for (int i = tid; i < 4096; i += 256) sW2[i] = W2[i];

    const int base = blockIdx.x * 256;
    const int row  = tid;
    const int pos  = base + row;
    const bool valid = (pos < P);

    uint2 pn = make_uint2(0u, 0u);
    float x0 = 0.f, x1 = 0.f, x2 = 0.f;
    if (valid) {
        pn = bucket2[pos];
        x0 = x[3 * pn.x + 0];
        x1 = x[3 * pn.x + 1];
        x2 = x[3 * pn.x + 2];
    }
    snode[row] = pn.y;
    __syncthreads();

    if (valid) {
        // pass 1: mean / var of layer-1 outputs (recompute-friendly: 3 FMA/ch)
        float sum = 0.f, sq = 0.f;
#pragma unroll 8
        for (int k = 0; k < 64; k++) {
            float4 w = sW1p[k];
            float y = fmaf(x0, w.x, fmaf(x1, w.y, fmaf(x2, w.z, w.w)));
            sum += y;
            sq = fmaf(y, y, sq);
        }
        const float mu = sum * (1.f / 64.f);
        float var = sq * (1.f / 64.f) - mu * mu;
        var = var > 0.f ? var : 0.f;
        const float rs = rsqrtf(var + EPS_LN);

        // pass 2: two 32-channel tiles; recompute y_k, normalize, FMA into acc
#pragma unroll
        for (int t2 = 0; t2 < 2; t2++) {
            float4 acc[8];
#pragma unroll
            for (int q = 0; q < 8; q++) acc[q] = *(const float4*)&sb2[t2 * 32 + 4 * q];
#pragma unroll 4
            for (int k = 0; k < 64; k++) {
                float4 w = sW1p[k];
                float y = fmaf(x0, w.x, fmaf(x1, w.y, fmaf(x2, w.z, w.w)));
                float a = fmaf((y - mu) * rs, sg1[k], sbe1[k]);
                a = a > 0.f ? a : 0.f;
                const float4* wr = (const float4*)&sW2[k * 64 + t2 * 32];  // wave-uniform broadcast
#pragma unroll
                for (int q = 0; q < 8; q++) {
                    float4 wv = wr[q];
                    acc[q].x = fmaf(a, wv.x, acc[q].x);
                    acc[q].y = fmaf(a, wv.y, acc[q].y);
                    acc[q].z = fmaf(a, wv.z, acc[q].z);
                    acc[q].w = fmaf(a, wv.w, acc[q].w);
                }
            }
#pragma unroll
            for (int q = 0; q < 8; q++) {
                sh[row * 33 + t2 * 16 + 2 * q]     = __float22bfloat162_rn(make_float2(acc[q].x, acc[q].y));
                sh[row * 33 + t2 * 16 + 2 * q + 1] = __float22bfloat162_rn(make_float2(acc[q].z, acc[q].w));
            }
        }
    }
    __syncthreads();

    // segmented max over the chunk's node range
    const int nValid = (P - base < 256) ? (P - base) : 256;
    if (nValid <= 0) return;
    const unsigned n0 = snode[0];
    const unsigned n1 = snode[nValid - 1];
    const unsigned bEnd = (unsigned)(base + nValid);
    const int wave = tid >> 6;
    const int lane = tid & 63;

    for (unsigned n = n0 + (unsigned)wave; n <= n1; n += 4) {
        const unsigned s = offsets[n];
        const unsigned e = offsets[n + 1];
        int lo = (int)(s > (unsigned)base ? s : (unsigned)base) - base;
        int hi = (int)(e < bEnd ? e : bEnd) - base;
        if (hi <= lo) continue;  // empty node inside range: leave 0
        float v = -3.402823466e38f;
        for (int r = lo; r < hi; r++) {
            __hip_bfloat162 h2 = sh[r * 33 + (lane >> 1)];
            float f = __bfloat162float((lane & 1) ? h2.y : h2.x);
            v = fmaxf(v, f);
        }
        const unsigned key = ordkey(v);
        unsigned* dst = &segord[(size_t)n * 64 + lane];
        if (s >= (unsigned)base && e <= bEnd) *dst = key;   // sole writer
        else atomicMax(dst, key);                            // chunk-boundary node
    }
}

// ---------------------------------------------------------------------------
// K5: decode segment maxima (0 -> empty -> 0), then
// MLP2: Linear(64,128) -> LN -> ReLU -> Linear(128,128), fp32.
// ---------------------------------------------------------------------------
__global__ __launch_bounds__(256) void mlp2_kernel(
    const unsigned* __restrict__ segord,
    const float* __restrict__ W3, const float* __restrict__ b3,
    const float* __restrict__ g2, const float* __restrict__ be2,
    const float* __restrict__ W4, const float* __restrict__ b4,
    float* __restrict__ out, int N)
{
    __shared__ float sW3[64 * 128];   // 32 KB
    __shared__ float sW4[128 * 128];  // 64 KB
    __shared__ float sb3[128], sg2[128], sbe2[128], sb4[128];
    __shared__ float s_s[2][64];
    __shared__ float s_u[2][128];
    __shared__ float red[2][2][2];

    const int tid = threadIdx.x;
    for (int i = tid; i < 64 * 128; i += 256) sW3[i] = W3[i];
    for (int i = tid; i < 128 * 128; i += 256) sW4[i] = W4[i];
    if (tid < 128) {
        sb3[tid]  = b3[tid];
        sg2[tid]  = g2[tid];
        sbe2[tid] = be2[tid];
        sb4[tid]  = b4[tid];
    }
    __syncthreads();

    const int half = tid >> 7;
    const int j    = tid & 127;
    const int waveInHalf = (tid >> 6) & 1;
    const int lane = tid & 63;

    for (int n0 = blockIdx.x * 2; n0 < N; n0 += gridDim.x * 2) {
        const int node = n0 + half;

        if (j < 64) {
            unsigned o = segord[(size_t)node * 64 + j];
            s_s[half][j] = (o == 0u) ? 0.f : orddecode(o);
        }
        __syncthreads();

        float t = sb3[j];
#pragma unroll 8
        for (int k = 0; k < 64; k++) t = fmaf(s_s[half][k], sW3[k * 128 + j], t);

        float s1 = t, s2 = t * t;
#pragma unroll
        for (int off = 32; off > 0; off >>= 1) {
            s1 += __shfl_down(s1, off);
            s2 += __shfl_down(s2, off);
        }
        if (lane == 0) { red[half][waveInHalf][0] = s1; red[half][waveInHalf][1] = s2; }
        __syncthreads();

        const float sumt  = red[half][0][0] + red[half][1][0];
        const float sumt2 = red[half][0][1] + red[half][1][1];
        const float mu  = sumt * (1.f / 128.f);
        const float var = sumt2 * (1.f / 128.f) - mu * mu;
        const float rsd = rsqrtf(var + EPS_LN);
        float u = fmaf((t - mu) * rsd, sg2[j], sbe2[j]);
        u = u > 0.f ? u : 0.f;
        s_u[half][j] = u;
        __syncthreads();

        float o = sb4[j];
#pragma unroll 8
        for (int k = 0; k < 128; k++) o = fmaf(s_u[half][k], sW4[k * 128 + j], o);
        out[(size_t)node * 128 + j] = o;
        __syncthreads();
    }
}

extern "C" void kernel_launch(void* const* d_in, const int* in_sizes, int n_in,
                              void* d_out, int out_size, void* d_ws, size_t ws_size,
                              hipStream_t stream) {
    const float* x    = (const float*)d_in[0];
    const int*   bidx = (const int*)d_in[1];
    const float* W1  = (const float*)d_in[3];
    const float* b1  = (const float*)d_in[4];
    const float* g1  = (const float*)d_in[5];
    const float* be1 = (const float*)d_in[6];
    const float* W2  = (const float*)d_in[7];
    const float* b2  = (const float*)d_in[8];
    const float* W3  = (const float*)d_in[9];
    const float* b3  = (const float*)d_in[10];
    const float* g2  = (const float*)d_in[11];
    const float* be2 = (const float*)d_in[12];
    const float* W4  = (const float*)d_in[13];
    const float* b4  = (const float*)d_in[14];

    const int P = in_sizes[0] / 3;
    const int N = out_size / 128;

    uintptr_t w = (uintptr_t)d_ws;
    auto align = [](uintptr_t v) { return (v + 255) & ~(uintptr_t)255; };
    unsigned* counts  = (unsigned*)align(w);                 w = (uintptr_t)(counts  + N);
    unsigned* offsets = (unsigned*)align(w);                 w = (uintptr_t)(offsets + N + 1);
    unsigned* cursor  = (unsigned*)align(w);                 w = (uintptr_t)(cursor  + N);
    uint2*    bucket2 = (uint2*)align(w);                    w = (uintptr_t)(bucket2 + P);
    unsigned* segord  = (unsigned*)align(w);

    hipMemsetAsync(counts, 0, (size_t)N * sizeof(unsigned), stream);
    hipMemsetAsync(segord, 0, (size_t)N * 64 * sizeof(unsigned), stream);

    const int gridP = (P + 255) / 256;
    hist_kernel<<<gridP, 256, 0, stream>>>(bidx, counts, P);
    scan_kernel<<<1, 1024, 0, stream>>>(counts, offsets, cursor, N);
    scatter_kernel<<<gridP, 256, 0, stream>>>(bidx, cursor, bucket2, P);

    fused_mlp1_pool_kernel<<<gridP, 256, 0, stream>>>(
        x, bucket2, offsets, W1, b1, g1, be1, W2, b2, segord, P);

    mlp2_kernel<<<256, 256, 0, stream>>>(
        segord, W3, b3, g2, be2, W4, b4, (float*)d_out, N);
}

// Round 4
// 818.583 us; speedup vs baseline: 7.1963x; 1.5780x over previous
//
#include <hip/hip_runtime.h>
#include <hip/hip_bf16.h>
#include <math.h>

#define EPS_LN 1e-5f

typedef __attribute__((ext_vector_type(8))) short bf16x8;
typedef __attribute__((ext_vector_type(4))) float f32x4;

// Monotone float->uint key; 0 encodes "never written" (= empty segment -> 0.0 later).
__device__ __forceinline__ unsigned ordkey(float f) {
    unsigned u = __float_as_uint(f);
    return (u & 0x80000000u) ? ~u : (u | 0x80000000u);
}
__device__ __forceinline__ float orddecode(unsigned o) {
    unsigned u = (o & 0x80000000u) ? (o & 0x7FFFFFFFu) : ~o;
    return __uint_as_float(u);
}
__device__ __forceinline__ unsigned short f2bf(float f) {
    __hip_bfloat16 h = __float2bfloat16(f);
    return *reinterpret_cast<unsigned short*>(&h);
}
__device__ __forceinline__ float bf2f(unsigned short u) {
    return __uint_as_float(((unsigned)u) << 16);
}

// ---------------------------------------------------------------------------
// K1: histogram of batch_idx -> counts[N]
// ---------------------------------------------------------------------------
__global__ __launch_bounds__(256) void hist_kernel(const int* __restrict__ bidx,
                                                   unsigned* __restrict__ counts, int P) {
    int p = blockIdx.x * 256 + threadIdx.x;
    if (p < P) atomicAdd(&counts[bidx[p]], 1u);
}

// ---------------------------------------------------------------------------
// K2: exclusive scan counts -> offsets[N+1]; cursor[N] = offsets[0..N-1]
// Single block, 1024 threads, 64 elements/thread (uint4 loads). N <= 65536.
// ---------------------------------------------------------------------------
__global__ __launch_bounds__(1024) void scan_kernel(const unsigned* __restrict__ counts,
                                                    unsigned* __restrict__ offsets,
                                                    unsigned* __restrict__ cursor, int N) {
    __shared__ unsigned waveTot[16];
    const int t = threadIdx.x;
    const int base = t * 64;
    unsigned local[64];
    unsigned s = 0;
    if (base + 64 <= N && ((N & 3) == 0)) {
        const uint4* c4 = (const uint4*)counts;
        for (int i = 0; i < 16; i++) {
            uint4 c = c4[t * 16 + i];
            local[4 * i + 0] = s; s += c.x;
            local[4 * i + 1] = s; s += c.y;
            local[4 * i + 2] = s; s += c.z;
            local[4 * i + 3] = s; s += c.w;
        }
    } else {
        for (int i = 0; i < 64; i++) {
            int idx = base + i;
            unsigned c = (idx < N) ? counts[idx] : 0u;
            local[i] = s;
            s += c;
        }
    }
    unsigned v = s;
    const int lane = t & 63;
    for (int off = 1; off < 64; off <<= 1) {
        unsigned u = __shfl_up(v, off);
        if (lane >= off) v += u;
    }
    if (lane == 63) waveTot[t >> 6] = v;
    __syncthreads();
    if (t == 0) {
        unsigned acc = 0;
        for (int w = 0; w < 16; w++) { unsigned tmp = waveTot[w]; waveTot[w] = acc; acc += tmp; }
    }
    __syncthreads();
    const unsigned chunkBase = waveTot[t >> 6] + (v - s);
    for (int i = 0; i < 64; i++) {
        int idx = base + i;
        if (idx < N) {
            unsigned o = chunkBase + local[i];
            offsets[idx] = o;
            cursor[idx]  = o;
        }
    }
    if (t == 1023) offsets[N] = chunkBase + s;
}

// ---------------------------------------------------------------------------
// K3: scatter (point, node) records into node buckets
// ---------------------------------------------------------------------------
__global__ __launch_bounds__(256) void scatter_kernel(const int* __restrict__ bidx,
                                                      unsigned* __restrict__ cursor,
                                                      uint2* __restrict__ bucket2, int P) {
    int p = blockIdx.x * 256 + threadIdx.x;
    if (p < P) {
        int n = bidx[p];
        unsigned pos = atomicAdd(&cursor[n], 1u);
        bucket2[pos] = make_uint2((unsigned)p, (unsigned)n);
    }
}

// ---------------------------------------------------------------------------
// K4: fused MLP1 + chunk-segmented max pool, W2 GEMM via MFMA.
// Block = 256 bucket positions. Phase 1: thread-per-point layer-1 + LN ->
// bf16 activations to LDS (stride 72 = 8*odd -> balanced banks). Phase 2:
// per-wave 64x64x64 MFMA GEMM (4 row-tiles x 4 col-tiles x 2 K-steps),
// h -> LDS bf16. Phase 3: block segmented max; boundary nodes atomicMax.
// LDS = 81.7 KB -> 2 blocks/CU.
// ---------------------------------------------------------------------------
__global__ __launch_bounds__(256, 2) void fused_mlp1_pool_kernel(
    const float* __restrict__ x, const uint2* __restrict__ bucket2,
    const unsigned* __restrict__ offsets,
    const float* __restrict__ W1, const float* __restrict__ b1,
    const float* __restrict__ g1, const float* __restrict__ be1,
    const float* __restrict__ W2, const float* __restrict__ b2,
    unsigned* __restrict__ segord, int P)
{
    __shared__ float4 sW1p[64];                        // (w0,w1,w2,b1) per channel
    __shared__ float sg1[64], sbe1[64], sb2[64];
    __shared__ __align__(16) unsigned short sW2t[64 * 72];  // B-frag layout [n][k], 9.2 KB
    __shared__ __align__(16) unsigned short sa[256 * 72];   // A activations [row][k], 36 KB
    __shared__ __align__(16) unsigned short shb[256 * 64];  // h output [row][ch], 32 KB
    __shared__ unsigned snode[256];

    const int tid = threadIdx.x;
    if (tid < 64) {
        sW1p[tid] = make_float4(W1[tid], W1[64 + tid], W1[128 + tid], b1[tid]);
        sg1[tid]  = g1[tid];
        sbe1[tid] = be1[tid];
        sb2[tid]  = b2[tid];
    }
    // W2 transposed to bf16 B-fragment layout: sW2t[n][k]
    for (int i = tid; i < 4096; i += 256) {
        int k = i >> 6, n = i & 63;
        sW2t[n * 72 + k] = f2bf(W2[i]);
    }

    const int base = blockIdx.x * 256;
    const int row  = tid;
    const int pos  = base + row;
    const bool valid = (pos < P);

    uint2 pn = make_uint2(0u, 0u);
    float x0 = 0.f, x1 = 0.f, x2 = 0.f;
    if (valid) {
        pn = bucket2[pos];
        x0 = x[3 * pn.x + 0];
        x1 = x[3 * pn.x + 1];
        x2 = x[3 * pn.x + 2];
    }
    snode[row] = pn.y;
    __syncthreads();

    // ---- Phase 1: layer-1 + LN + ReLU, bf16 -> sa (invalid rows compute x=0; harmless)
    {
        float sum = 0.f, sq = 0.f;
#pragma unroll 8
        for (int k = 0; k < 64; k++) {
            float4 w = sW1p[k];
            float y = fmaf(x0, w.x, fmaf(x1, w.y, fmaf(x2, w.z, w.w)));
            sum += y;
            sq = fmaf(y, y, sq);
        }
        const float mu = sum * (1.f / 64.f);
        float var = sq * (1.f / 64.f) - mu * mu;
        var = var > 0.f ? var : 0.f;
        const float rs = rsqrtf(var + EPS_LN);

#pragma unroll
        for (int kb = 0; kb < 8; kb++) {
            bf16x8 v;
#pragma unroll
            for (int u = 0; u < 8; u++) {
                int k = kb * 8 + u;
                float4 w = sW1p[k];
                float y = fmaf(x0, w.x, fmaf(x1, w.y, fmaf(x2, w.z, w.w)));
                float a = fmaf((y - mu) * rs, sg1[k], sbe1[k]);
                a = a > 0.f ? a : 0.f;
                v[u] = (short)f2bf(a);
            }
            *reinterpret_cast<bf16x8*>(&sa[row * 72 + kb * 8]) = v;
        }
    }
    // no barrier: each wave MFMAs only its own 64 rows (written by itself);
    // sW2t was written pre-barrier above.

    // ---- Phase 2: h[64 rows x 64 ch] = a @ W2 + b2 via MFMA 16x16x32 bf16
    {
        const int wv   = tid >> 6;
        const int lane = tid & 63;
        const int m    = lane & 15;
        const int quad = lane >> 4;

        bf16x8 bfrag[4][2];
#pragma unroll
        for (int nt = 0; nt < 4; nt++)
#pragma unroll
            for (int s = 0; s < 2; s++)
                bfrag[nt][s] = *reinterpret_cast<const bf16x8*>(
                    &sW2t[(nt * 16 + m) * 72 + s * 32 + quad * 8]);

#pragma unroll
        for (int rt = 0; rt < 4; rt++) {
            const int arow = wv * 64 + rt * 16 + m;
            bf16x8 af0 = *reinterpret_cast<const bf16x8*>(&sa[arow * 72 + quad * 8]);
            bf16x8 af1 = *reinterpret_cast<const bf16x8*>(&sa[arow * 72 + 32 + quad * 8]);
#pragma unroll
            for (int nt = 0; nt < 4; nt++) {
                const float bc = sb2[nt * 16 + m];
                f32x4 acc = {bc, bc, bc, bc};
                acc = __builtin_amdgcn_mfma_f32_16x16x32_bf16(af0, bfrag[nt][0], acc, 0, 0, 0);
                acc = __builtin_amdgcn_mfma_f32_16x16x32_bf16(af1, bfrag[nt][1], acc, 0, 0, 0);
                // C/D layout: col = lane&15, row = quad*4 + r
#pragma unroll
                for (int r = 0; r < 4; r++) {
                    const int orow = wv * 64 + rt * 16 + quad * 4 + r;
                    shb[orow * 64 + nt * 16 + m] = f2bf(acc[r]);
                }
            }
        }
    }
    __syncthreads();

    // ---- Phase 3: segmented max over the chunk's node range
    const int nValid = (P - base < 256) ? (P - base) : 256;
    if (nValid <= 0) return;
    const unsigned n0 = snode[0];
    const unsigned n1 = snode[nValid - 1];
    const unsigned bEnd = (unsigned)(base + nValid);
    const int wave = tid >> 6;
    const int lane = tid & 63;

    for (unsigned n = n0 + (unsigned)wave; n <= n1; n += 4) {
        const unsigned s = offsets[n];
        const unsigned e = offsets[n + 1];
        int lo = (int)(s > (unsigned)base ? s : (unsigned)base) - base;
        int hi = (int)(e < bEnd ? e : bEnd) - base;
        if (hi <= lo) continue;  // empty node inside range: leave 0
        float v = -3.402823466e38f;
        for (int r = lo; r < hi; r++) {
            v = fmaxf(v, bf2f(shb[r * 64 + lane]));
        }
        const unsigned key = ordkey(v);
        unsigned* dst = &segord[(size_t)n * 64 + lane];
        if (s >= (unsigned)base && e <= bEnd) *dst = key;   // sole writer
        else atomicMax(dst, key);                            // chunk-boundary node
    }
}

// ---------------------------------------------------------------------------
// K5: decode maxima (0 -> empty -> 0), MLP2 with 4-node ILP.
// Block = 256 = 2 halves x 128 j-threads; each half processes 4 nodes per
// iteration (4 independent FMA chains amortize each weight ds_read 4x).
// ---------------------------------------------------------------------------
__global__ __launch_bounds__(256) void mlp2_kernel(
    const unsigned* __restrict__ segord,
    const float* __restrict__ W3, const float* __restrict__ b3,
    const float* __restrict__ g2, const float* __restrict__ be2,
    const float* __restrict__ W4, const float* __restrict__ b4,
    float* __restrict__ out, int N)
{
    __shared__ float sW3[64 * 128];    // 32 KB
    __shared__ float sW4[128 * 128];   // 64 KB
    __shared__ float sb3[128], sg2[128], sbe2[128], sb4[128];
    __shared__ float2 s2m[8 * 32];     // 8 nodes x 32 channel-pairs
    __shared__ float su[8 * 128];      // 8 nodes x 128 activations
    __shared__ float red[2][2][4][2];  // [half][waveInHalf][i][{sum,sumsq}]

    const int tid = threadIdx.x;
    {
        const float4* W3v = (const float4*)W3;
        const float4* W4v = (const float4*)W4;
        float4* s3v = (float4*)sW3;
        float4* s4v = (float4*)sW4;
        for (int i = tid; i < 2048; i += 256) s3v[i] = W3v[i];
        for (int i = tid; i < 4096; i += 256) s4v[i] = W4v[i];
    }
    if (tid < 128) {
        sb3[tid]  = b3[tid];
        sg2[tid]  = g2[tid];
        sbe2[tid] = be2[tid];
        sb4[tid]  = b4[tid];
    }
    __syncthreads();

    const int half = tid >> 7;
    const int j    = tid & 127;
    const int wIH  = (tid >> 6) & 1;
    const int lane = tid & 63;

    for (int nb = blockIdx.x * 8; nb < N; nb += gridDim.x * 8) {
        // load + decode s for nodes nb..nb+7 (256 channel-pairs, coalesced)
        {
            const int nodeL = tid >> 5;      // 0..7
            const int kp    = tid & 31;      // channel pair
            const int node  = nb + nodeL;
            float2 v = make_float2(0.f, 0.f);
            if (node < N) {
                unsigned o0 = segord[(size_t)node * 64 + 2 * kp];
                unsigned o1 = segord[(size_t)node * 64 + 2 * kp + 1];
                v.x = o0 ? orddecode(o0) : 0.f;
                v.y = o1 ? orddecode(o1) : 0.f;
            }
            s2m[nodeL * 32 + kp] = v;
        }
        __syncthreads();

        // t = s @ W3 + b3 for 4 nodes at once
        float t0 = sb3[j], t1 = t0, t2 = t0, t3 = t0;
        const int gb = half * 4 * 32;
#pragma unroll 8
        for (int k2 = 0; k2 < 32; k2++) {
            float w0 = sW3[(2 * k2) * 128 + j];
            float w1 = sW3[(2 * k2 + 1) * 128 + j];
            float2 v0 = s2m[gb + 0 * 32 + k2];
            float2 v1 = s2m[gb + 1 * 32 + k2];
            float2 v2 = s2m[gb + 2 * 32 + k2];
            float2 v3 = s2m[gb + 3 * 32 + k2];
            t0 = fmaf(w0, v0.x, fmaf(w1, v0.y, t0));
            t1 = fmaf(w0, v1.x, fmaf(w1, v1.y, t1));
            t2 = fmaf(w0, v2.x, fmaf(w1, v2.y, t2));
            t3 = fmaf(w0, v3.x, fmaf(w1, v3.y, t3));
        }

        // LN over 128 j's (2 waves per half), 4 nodes
        float s1[4] = {t0, t1, t2, t3};
        float sq[4] = {t0 * t0, t1 * t1, t2 * t2, t3 * t3};
#pragma unroll
        for (int off = 32; off > 0; off >>= 1) {
#pragma unroll
            for (int i = 0; i < 4; i++) {
                s1[i] += __shfl_down(s1[i], off);
                sq[i] += __shfl_down(sq[i], off);
            }
        }
        if (lane == 0) {
#pragma unroll
            for (int i = 0; i < 4; i++) {
                red[half][wIH][i][0] = s1[i];
                red[half][wIH][i][1] = sq[i];
            }
        }
        __syncthreads();

        float tv[4] = {t0, t1, t2, t3};
#pragma unroll
        for (int i = 0; i < 4; i++) {
            const float sum  = red[half][0][i][0] + red[half][1][i][0];
            const float sums = red[half][0][i][1] + red[half][1][i][1];
            const float mu  = sum * (1.f / 128.f);
            const float var = sums * (1.f / 128.f) - mu * mu;
            const float rsd = rsqrtf(var + EPS_LN);
            float u = fmaf((tv[i] - mu) * rsd, sg2[j], sbe2[j]);
            u = u > 0.f ? u : 0.f;
            su[(half * 4 + i) * 128 + j] = u;
        }
        __syncthreads();

        // o = u @ W4 + b4 for 4 nodes at once
        float o0 = sb4[j], o1 = o0, o2 = o0, o3 = o0;
        const int ub = half * 4 * 128;
#pragma unroll 8
        for (int k2 = 0; k2 < 64; k2++) {
            float w0 = sW4[(2 * k2) * 128 + j];
            float w1 = sW4[(2 * k2 + 1) * 128 + j];
            float2 u0 = *(const float2*)&su[ub + 0 * 128 + 2 * k2];
            float2 u1 = *(const float2*)&su[ub + 1 * 128 + 2 * k2];
            float2 u2 = *(const float2*)&su[ub + 2 * 128 + 2 * k2];
            float2 u3 = *(const float2*)&su[ub + 3 * 128 + 2 * k2];
            o0 = fmaf(w0, u0.x, fmaf(w1, u0.y, o0));
            o1 = fmaf(w0, u1.x, fmaf(w1, u1.y, o1));
            o2 = fmaf(w0, u2.x, fmaf(w1, u2.y, o2));
            o3 = fmaf(w0, u3.x, fmaf(w1, u3.y, o3));
        }
        const float ov[4] = {o0, o1, o2, o3};
#pragma unroll
        for (int i = 0; i < 4; i++) {
            const int node = nb + half * 4 + i;
            if (node < N) out[(size_t)node * 128 + j] = ov[i];
        }
        __syncthreads();   // protect s2m/su/red for next iteration
    }
}

extern "C" void kernel_launch(void* const* d_in, const int* in_sizes, int n_in,
                              void* d_out, int out_size, void* d_ws, size_t ws_size,
                              hipStream_t stream) {
    const float* x    = (const float*)d_in[0];
    const int*   bidx = (const int*)d_in[1];
    const float* W1  = (const float*)d_in[3];
    const float* b1  = (const float*)d_in[4];
    const float* g1  = (const float*)d_in[5];
    const float* be1 = (const float*)d_in[6];
    const float* W2  = (const float*)d_in[7];
    const float* b2  = (const float*)d_in[8];
    const float* W3  = (const float*)d_in[9];
    const float* b3  = (const float*)d_in[10];
    const float* g2  = (const float*)d_in[11];
    const float* be2 = (const float*)d_in[12];
    const float* W4  = (const float*)d_in[13];
    const float* b4  = (const float*)d_in[14];

    const int P = in_sizes[0] / 3;
    const int N = out_size / 128;

    uintptr_t w = (uintptr_t)d_ws;
    auto align = [](uintptr_t v) { return (v + 255) & ~(uintptr_t)255; };
    unsigned* counts  = (unsigned*)align(w);                 w = (uintptr_t)(counts  + N);
    unsigned* offsets = (unsigned*)align(w);                 w = (uintptr_t)(offsets + N + 1);
    unsigned* cursor  = (unsigned*)align(w);                 w = (uintptr_t)(cursor  + N);
    uint2*    bucket2 = (uint2*)align(w);                    w = (uintptr_t)(bucket2 + P);
    unsigned* segord  = (unsigned*)align(w);

    hipMemsetAsync(counts, 0, (size_t)N * sizeof(unsigned), stream);
    hipMemsetAsync(segord, 0, (size_t)N * 64 * sizeof(unsigned), stream);

    const int gridP = (P + 255) / 256;
    hist_kernel<<<gridP, 256, 0, stream>>>(bidx, counts, P);
    scan_kernel<<<1, 1024, 0, stream>>>(counts, offsets, cursor, N);
    scatter_kernel<<<gridP, 256, 0, stream>>>(bidx, cursor, bucket2, P);

    fused_mlp1_pool_kernel<<<gridP, 256, 0, stream>>>(
        x, bucket2, offsets, W1, b1, g1, be1, W2, b2, segord, P);

    mlp2_kernel<<<256, 256, 0, stream>>>(
        segord, W3, b3, g2, be2, W4, b4, (float*)d_out, N);
}

// Round 5
// 680.523 us; speedup vs baseline: 8.6563x; 1.2029x over previous
//
#include <hip/hip_runtime.h>
#include <hip/hip_bf16.h>
#include <math.h>

#define EPS_LN 1e-5f

typedef __attribute__((ext_vector_type(8))) short bf16x8;
typedef __attribute__((ext_vector_type(4))) float f32x4;

// Monotone float->uint key; 0 encodes "never written" (= empty segment -> 0.0 later).
__device__ __forceinline__ unsigned ordkey(float f) {
    unsigned u = __float_as_uint(f);
    return (u & 0x80000000u) ? ~u : (u | 0x80000000u);
}
__device__ __forceinline__ float orddecode(unsigned o) {
    unsigned u = (o & 0x80000000u) ? (o & 0x7FFFFFFFu) : ~o;
    return __uint_as_float(u);
}
__device__ __forceinline__ unsigned short f2bf(float f) {
    __hip_bfloat16 h = __float2bfloat16(f);
    return *reinterpret_cast<unsigned short*>(&h);
}
__device__ __forceinline__ float bf2f(unsigned short u) {
    return __uint_as_float(((unsigned)u) << 16);
}

// ---------------------------------------------------------------------------
// K1: histogram of batch_idx -> counts[N], 4 points/thread (int4 loads)
// ---------------------------------------------------------------------------
__global__ __launch_bounds__(256) void hist_kernel(const int* __restrict__ bidx,
                                                   unsigned* __restrict__ counts, int P) {
    int p0 = (blockIdx.x * 256 + threadIdx.x) * 4;
    if (p0 + 3 < P) {
        int4 n4 = *(const int4*)(bidx + p0);
        atomicAdd(&counts[n4.x], 1u);
        atomicAdd(&counts[n4.y], 1u);
        atomicAdd(&counts[n4.z], 1u);
        atomicAdd(&counts[n4.w], 1u);
    } else {
        for (int p = p0; p < P; p++) atomicAdd(&counts[bidx[p]], 1u);
    }
}

// ---------------------------------------------------------------------------
// K2: exclusive scan counts -> offsets[N+1]; cursor[N] = offsets[0..N-1]
// Single block, 1024 threads, 64 elements/thread (uint4 loads). N <= 65536.
// ---------------------------------------------------------------------------
__global__ __launch_bounds__(1024) void scan_kernel(const unsigned* __restrict__ counts,
                                                    unsigned* __restrict__ offsets,
                                                    unsigned* __restrict__ cursor, int N) {
    __shared__ unsigned waveTot[16];
    const int t = threadIdx.x;
    const int base = t * 64;
    unsigned local[64];
    unsigned s = 0;
    if (base + 64 <= N && ((N & 3) == 0)) {
        const uint4* c4 = (const uint4*)counts;
        for (int i = 0; i < 16; i++) {
            uint4 c = c4[t * 16 + i];
            local[4 * i + 0] = s; s += c.x;
            local[4 * i + 1] = s; s += c.y;
            local[4 * i + 2] = s; s += c.z;
            local[4 * i + 3] = s; s += c.w;
        }
    } else {
        for (int i = 0; i < 64; i++) {
            int idx = base + i;
            unsigned c = (idx < N) ? counts[idx] : 0u;
            local[i] = s;
            s += c;
        }
    }
    unsigned v = s;
    const int lane = t & 63;
    for (int off = 1; off < 64; off <<= 1) {
        unsigned u = __shfl_up(v, off);
        if (lane >= off) v += u;
    }
    if (lane == 63) waveTot[t >> 6] = v;
    __syncthreads();
    if (t == 0) {
        unsigned acc = 0;
        for (int w = 0; w < 16; w++) { unsigned tmp = waveTot[w]; waveTot[w] = acc; acc += tmp; }
    }
    __syncthreads();
    const unsigned chunkBase = waveTot[t >> 6] + (v - s);
    for (int i = 0; i < 64; i++) {
        int idx = base + i;
        if (idx < N) {
            unsigned o = chunkBase + local[i];
            offsets[idx] = o;
            cursor[idx]  = o;
        }
    }
    if (t == 1023) offsets[N] = chunkBase + s;
}

// ---------------------------------------------------------------------------
// K3: scatter (x0,x1,x2,node) float4 records into bucket order.
// Coalesced x read here so the fused kernel never random-gathers x.
// ---------------------------------------------------------------------------
__global__ __launch_bounds__(256) void scatter_kernel(const int* __restrict__ bidx,
                                                      const float* __restrict__ x,
                                                      unsigned* __restrict__ cursor,
                                                      float4* __restrict__ xb, int P) {
    int p = blockIdx.x * 256 + threadIdx.x;
    if (p < P) {
        int n = bidx[p];
        float x0 = x[3 * p + 0];
        float x1 = x[3 * p + 1];
        float x2 = x[3 * p + 2];
        unsigned pos = atomicAdd(&cursor[n], 1u);
        xb[pos] = make_float4(x0, x1, x2, __uint_as_float((unsigned)n));
    }
}

// ---------------------------------------------------------------------------
// K4: fused MLP1 + chunk-segmented max pool, W2 GEMM via MFMA.
// Block = 256 bucket positions, coalesced float4 xb reads. Phase 1:
// single-pass layer-1 (a[64] in VGPRs) + LN -> bf16 to sa (stride 72).
// Phase 2: per-wave 64x64x64 MFMA (16x16x32 bf16), h -> shb stride 64 with
// quad-XOR column swizzle (4-way instead of 8-way store conflicts).
// Phase 3: block segmented max; boundary nodes atomicMax.
// LDS ~81 KB -> 2 blocks/CU.
// ---------------------------------------------------------------------------
__global__ __launch_bounds__(256, 2) void fused_mlp1_pool_kernel(
    const float4* __restrict__ xb, const unsigned* __restrict__ offsets,
    const float* __restrict__ W1, const float* __restrict__ b1,
    const float* __restrict__ g1, const float* __restrict__ be1,
    const float* __restrict__ W2, const float* __restrict__ b2,
    unsigned* __restrict__ segord, int P)
{
    __shared__ float4 sW1p[64];                        // (w0,w1,w2,b1) per channel
    __shared__ float sg1[64], sbe1[64], sb2[64];
    __shared__ __align__(16) unsigned short sW2t[64 * 72];  // B-frag layout [n][k], 9.2 KB
    __shared__ __align__(16) unsigned short sa[256 * 72];   // A activations [row][k], 36 KB
    __shared__ __align__(16) unsigned short shb[256 * 64];  // h output [row][ch^swz], 32 KB
    __shared__ unsigned sn01[2];

    const int tid = threadIdx.x;
    if (tid < 64) {
        sW1p[tid] = make_float4(W1[tid], W1[64 + tid], W1[128 + tid], b1[tid]);
        sg1[tid]  = g1[tid];
        sbe1[tid] = be1[tid];
        sb2[tid]  = b2[tid];
    }
    // W2 transposed to bf16 B-fragment layout: sW2t[n][k]
    for (int i = tid; i < 4096; i += 256) {
        int k = i >> 6, n = i & 63;
        sW2t[n * 72 + k] = f2bf(W2[i]);
    }

    const int base = blockIdx.x * 256;
    const int row  = tid;
    const int pos  = base + row;
    const bool valid = (pos < P);

    float x0 = 0.f, x1 = 0.f, x2 = 0.f;
    unsigned node = 0u;
    if (valid) {
        float4 v = xb[pos];
        x0 = v.x; x1 = v.y; x2 = v.z;
        node = __float_as_uint(v.w);
        if (row == 0) sn01[0] = node;
        if (row == 255 || pos == P - 1) sn01[1] = node;
    }
    __syncthreads();

    // ---- Phase 1: single-pass layer-1 + LN + ReLU, bf16 -> sa
    {
        float a[64];
        float sum = 0.f, sq = 0.f;
#pragma unroll
        for (int k = 0; k < 64; k++) {
            float4 w = sW1p[k];
            float y = fmaf(x0, w.x, fmaf(x1, w.y, fmaf(x2, w.z, w.w)));
            a[k] = y;
            sum += y;
            sq = fmaf(y, y, sq);
        }
        const float mu = sum * (1.f / 64.f);
        float var = sq * (1.f / 64.f) - mu * mu;
        var = var > 0.f ? var : 0.f;
        const float rs = rsqrtf(var + EPS_LN);

#pragma unroll
        for (int kb = 0; kb < 8; kb++) {
            bf16x8 v;
#pragma unroll
            for (int u = 0; u < 8; u++) {
                int k = kb * 8 + u;
                float aa = fmaf((a[k] - mu) * rs, sg1[k], sbe1[k]);
                aa = aa > 0.f ? aa : 0.f;
                v[u] = (short)f2bf(aa);
            }
            *reinterpret_cast<bf16x8*>(&sa[row * 72 + kb * 8]) = v;
        }
    }
    // no barrier: each wave MFMAs only its own 64 rows (written by itself);
    // sW2t/sW1p were written before the first barrier.

    // ---- Phase 2: h[64 rows x 64 ch] = a @ W2 + b2 via MFMA 16x16x32 bf16
    {
        const int wv   = tid >> 6;
        const int lane = tid & 63;
        const int m    = lane & 15;
        const int quad = lane >> 4;

        bf16x8 bfrag[4][2];
#pragma unroll
        for (int nt = 0; nt < 4; nt++)
#pragma unroll
            for (int s = 0; s < 2; s++)
                bfrag[nt][s] = *reinterpret_cast<const bf16x8*>(
                    &sW2t[(nt * 16 + m) * 72 + s * 32 + quad * 8]);

#pragma unroll
        for (int rt = 0; rt < 4; rt++) {
            const int arow = wv * 64 + rt * 16 + m;
            bf16x8 af0 = *reinterpret_cast<const bf16x8*>(&sa[arow * 72 + quad * 8]);
            bf16x8 af1 = *reinterpret_cast<const bf16x8*>(&sa[arow * 72 + 32 + quad * 8]);
#pragma unroll
            for (int nt = 0; nt < 4; nt++) {
                const float bc = sb2[nt * 16 + m];
                f32x4 acc = {bc, bc, bc, bc};
                acc = __builtin_amdgcn_mfma_f32_16x16x32_bf16(af0, bfrag[nt][0], acc, 0, 0, 0);
                acc = __builtin_amdgcn_mfma_f32_16x16x32_bf16(af1, bfrag[nt][1], acc, 0, 0, 0);
                // C/D layout: col = lane&15, row = quad*4 + r; column XOR-swizzled store
#pragma unroll
                for (int r = 0; r < 4; r++) {
                    const int orow = wv * 64 + rt * 16 + quad * 4 + r;
                    const int col  = nt * 16 + m;
                    shb[orow * 64 + (col ^ ((orow & 4) << 2))] = f2bf(acc[r]);
                }
            }
        }
    }
    __syncthreads();

    // ---- Phase 3: segmented max over the chunk's node range
    const int nValid = (P - base < 256) ? (P - base) : 256;
    if (nValid <= 0) return;
    const unsigned n0 = sn01[0];
    const unsigned n1 = sn01[1];
    const unsigned bEnd = (unsigned)(base + nValid);
    const int wave = tid >> 6;
    const int lane = tid & 63;

    for (unsigned n = n0 + (unsigned)wave; n <= n1; n += 4) {
        const unsigned s = offsets[n];
        const unsigned e = offsets[n + 1];
        int lo = (int)(s > (unsigned)base ? s : (unsigned)base) - base;
        int hi = (int)(e < bEnd ? e : bEnd) - base;
        if (hi <= lo) continue;  // empty node inside range: leave 0
        float v = -3.402823466e38f;
        for (int r = lo; r < hi; r++) {
            v = fmaxf(v, bf2f(shb[r * 64 + (lane ^ ((r & 4) << 2))]));
        }
        const unsigned key = ordkey(v);
        unsigned* dst = &segord[(size_t)n * 64 + lane];
        if (s >= (unsigned)base && e <= bEnd) *dst = key;   // sole writer
        else atomicMax(dst, key);                            // chunk-boundary node
    }
}

// ---------------------------------------------------------------------------
// K5: decode maxima (0 -> empty -> 0), MLP2 with 4-node ILP.
// W3 in LDS (32 KB); W4 streamed from global (L2-resident, coalesced);
// per-j params in registers. LDS ~39 KB -> 4 blocks/CU.
// ---------------------------------------------------------------------------
__global__ __launch_bounds__(256, 4) void mlp2_kernel(
    const unsigned* __restrict__ segord,
    const float* __restrict__ W3, const float* __restrict__ b3,
    const float* __restrict__ g2, const float* __restrict__ be2,
    const float* __restrict__ W4, const float* __restrict__ b4,
    float* __restrict__ out, int N)
{
    __shared__ float sW3[64 * 128];    // 32 KB
    __shared__ float2 s2m[8 * 32];     // 8 nodes x 32 channel-pairs
    __shared__ float su[8 * 128];      // 8 nodes x 128 activations
    __shared__ float red[2][2][4][2];  // [half][waveInHalf][i][{sum,sumsq}]

    const int tid = threadIdx.x;
    {
        const float4* W3v = (const float4*)W3;
        float4* s3v = (float4*)sW3;
        for (int i = tid; i < 2048; i += 256) s3v[i] = W3v[i];
    }

    const int half = tid >> 7;
    const int j    = tid & 127;
    const int wIH  = (tid >> 6) & 1;
    const int lane = tid & 63;

    // per-j params in registers (coalesced global scalar loads)
    const float rb3  = b3[j];
    const float rg2  = g2[j];
    const float rbe2 = be2[j];
    const float rb4  = b4[j];
    __syncthreads();

    for (int nb = blockIdx.x * 8; nb < N; nb += gridDim.x * 8) {
        // load + decode s for nodes nb..nb+7 (coalesced)
        {
            const int nodeL = tid >> 5;      // 0..7
            const int kp    = tid & 31;      // channel pair
            const int node  = nb + nodeL;
            float2 v = make_float2(0.f, 0.f);
            if (node < N) {
                unsigned o0 = segord[(size_t)node * 64 + 2 * kp];
                unsigned o1 = segord[(size_t)node * 64 + 2 * kp + 1];
                v.x = o0 ? orddecode(o0) : 0.f;
                v.y = o1 ? orddecode(o1) : 0.f;
            }
            s2m[nodeL * 32 + kp] = v;
        }
        __syncthreads();

        // t = s @ W3 + b3 for 4 nodes at once (W3 from LDS)
        float t0 = rb3, t1 = rb3, t2 = rb3, t3 = rb3;
        const int gb = half * 4 * 32;
#pragma unroll 8
        for (int k2 = 0; k2 < 32; k2++) {
            float w0 = sW3[(2 * k2) * 128 + j];
            float w1 = sW3[(2 * k2 + 1) * 128 + j];
            float2 v0 = s2m[gb + 0 * 32 + k2];
            float2 v1 = s2m[gb + 1 * 32 + k2];
            float2 v2 = s2m[gb + 2 * 32 + k2];
            float2 v3 = s2m[gb + 3 * 32 + k2];
            t0 = fmaf(w0, v0.x, fmaf(w1, v0.y, t0));
            t1 = fmaf(w0, v1.x, fmaf(w1, v1.y, t1));
            t2 = fmaf(w0, v2.x, fmaf(w1, v2.y, t2));
            t3 = fmaf(w0, v3.x, fmaf(w1, v3.y, t3));
        }

        // LN over 128 j's (2 waves per half), 4 nodes
        float s1[4] = {t0, t1, t2, t3};
        float sq[4] = {t0 * t0, t1 * t1, t2 * t2, t3 * t3};
#pragma unroll
        for (int off = 32; off > 0; off >>= 1) {
#pragma unroll
            for (int i = 0; i < 4; i++) {
                s1[i] += __shfl_down(s1[i], off);
                sq[i] += __shfl_down(sq[i], off);
            }
        }
        if (lane == 0) {
#pragma unroll
            for (int i = 0; i < 4; i++) {
                red[half][wIH][i][0] = s1[i];
                red[half][wIH][i][1] = sq[i];
            }
        }
        __syncthreads();

        const float tv[4] = {t0, t1, t2, t3};
#pragma unroll
        for (int i = 0; i < 4; i++) {
            const float sum  = red[half][0][i][0] + red[half][1][i][0];
            const float sums = red[half][0][i][1] + red[half][1][i][1];
            const float mu  = sum * (1.f / 128.f);
            const float var = sums * (1.f / 128.f) - mu * mu;
            const float rsd = rsqrtf(var + EPS_LN);
            float u = fmaf((tv[i] - mu) * rsd, rg2, rbe2);
            u = u > 0.f ? u : 0.f;
            su[(half * 4 + i) * 128 + j] = u;
        }
        __syncthreads();

        // o = u @ W4 + b4 for 4 nodes at once (W4 streamed from global/L2)
        float o0 = rb4, o1 = rb4, o2 = rb4, o3 = rb4;
        const int ub = half * 4 * 128;
#pragma unroll 8
        for (int k2 = 0; k2 < 64; k2++) {
            float w0 = W4[(2 * k2) * 128 + j];
            float w1 = W4[(2 * k2 + 1) * 128 + j];
            float2 u0 = *(const float2*)&su[ub + 0 * 128 + 2 * k2];
            float2 u1 = *(const float2*)&su[ub + 1 * 128 + 2 * k2];
            float2 u2 = *(const float2*)&su[ub + 2 * 128 + 2 * k2];
            float2 u3 = *(const float2*)&su[ub + 3 * 128 + 2 * k2];
            o0 = fmaf(w0, u0.x, fmaf(w1, u0.y, o0));
            o1 = fmaf(w0, u1.x, fmaf(w1, u1.y, o1));
            o2 = fmaf(w0, u2.x, fmaf(w1, u2.y, o2));
            o3 = fmaf(w0, u3.x, fmaf(w1, u3.y, o3));
        }
        const float ov[4] = {o0, o1, o2, o3};
#pragma unroll
        for (int i = 0; i < 4; i++) {
            const int node = nb + half * 4 + i;
            if (node < N) out[(size_t)node * 128 + j] = ov[i];
        }
        __syncthreads();   // protect s2m/su/red for next iteration
    }
}

extern "C" void kernel_launch(void* const* d_in, const int* in_sizes, int n_in,
                              void* d_out, int out_size, void* d_ws, size_t ws_size,
                              hipStream_t stream) {
    const float* x    = (const float*)d_in[0];
    const int*   bidx = (const int*)d_in[1];
    const float* W1  = (const float*)d_in[3];
    const float* b1  = (const float*)d_in[4];
    const float* g1  = (const float*)d_in[5];
    const float* be1 = (const float*)d_in[6];
    const float* W2  = (const float*)d_in[7];
    const float* b2  = (const float*)d_in[8];
    const float* W3  = (const float*)d_in[9];
    const float* b3  = (const float*)d_in[10];
    const float* g2  = (const float*)d_in[11];
    const float* be2 = (const float*)d_in[12];
    const float* W4  = (const float*)d_in[13];
    const float* b4  = (const float*)d_in[14];

    const int P = in_sizes[0] / 3;
    const int N = out_size / 128;

    uintptr_t w = (uintptr_t)d_ws;
    auto align = [](uintptr_t v) { return (v + 255) & ~(uintptr_t)255; };
    unsigned* counts  = (unsigned*)align(w);                 w = (uintptr_t)(counts  + N);
    unsigned* offsets = (unsigned*)align(w);                 w = (uintptr_t)(offsets + N + 1);
    unsigned* cursor  = (unsigned*)align(w);                 w = (uintptr_t)(cursor  + N);
    float4*   xb      = (float4*)align(w);                   w = (uintptr_t)(xb      + P);
    unsigned* segord  = (unsigned*)align(w);

    hipMemsetAsync(counts, 0, (size_t)N * sizeof(unsigned), stream);
    hipMemsetAsync(segord, 0, (size_t)N * 64 * sizeof(unsigned), stream);

    hist_kernel<<<(P + 1023) / 1024, 256, 0, stream>>>(bidx, counts, P);
    scan_kernel<<<1, 1024, 0, stream>>>(counts, offsets, cursor, N);
    scatter_kernel<<<(P + 255) / 256, 256, 0, stream>>>(bidx, x, cursor, xb, P);

    fused_mlp1_pool_kernel<<<(P + 255) / 256, 256, 0, stream>>>(
        xb, offsets, W1, b1, g1, be1, W2, b2, segord, P);

    mlp2_kernel<<<1024, 256, 0, stream>>>(
        segord, W3, b3, g2, be2, W4, b4, (float*)d_out, N);
}

// Round 6
// 606.848 us; speedup vs baseline: 9.7072x; 1.1214x over previous
//
#include <hip/hip_runtime.h>
#include <hip/hip_bf16.h>
#include <math.h>

#define EPS_LN 1e-5f

typedef __attribute__((ext_vector_type(8))) short bf16x8;
typedef __attribute__((ext_vector_type(4))) float f32x4;

__device__ __forceinline__ unsigned ordkey(float f) {
    unsigned u = __float_as_uint(f);
    return (u & 0x80000000u) ? ~u : (u | 0x80000000u);
}
__device__ __forceinline__ float orddecode(unsigned o) {
    unsigned u = (o & 0x80000000u) ? (o & 0x7FFFFFFFu) : ~o;
    return __uint_as_float(u);
}
__device__ __forceinline__ unsigned short f2bf(float f) {
    __hip_bfloat16 h = __float2bfloat16(f);
    return *reinterpret_cast<unsigned short*>(&h);
}
__device__ __forceinline__ float bf2f(unsigned short u) {
    return __uint_as_float(((unsigned)u) << 16);
}
__device__ __forceinline__ float decseg(unsigned o) { return o ? orddecode(o) : 0.f; }

// ---------------------------------------------------------------------------
// K0: prep — pack params once per call.
//  pW1e[64] float4 = (W1[0][k],W1[1][k],W1[2][k],b1[k])
//  pGB[64]  float2 = (g1[k], be1[k])
//  pSG[16]  float  = S[4] then Gu[10]  (S=sum w~, G=sum w~ w~^T upper-tri)
//  pW2t bf16 [64][72]  (B-frag layout, padded)
//  W3th/W3tl bf16 [128][64]  hi/lo split of W3^T
//  W4th/W4tl bf16 [128][128] hi/lo split of W4^T
// ---------------------------------------------------------------------------
__global__ __launch_bounds__(256) void prep_kernel(
    const float* __restrict__ W1, const float* __restrict__ b1,
    const float* __restrict__ g1, const float* __restrict__ be1,
    const float* __restrict__ W2,
    const float* __restrict__ W3, const float* __restrict__ W4,
    float* __restrict__ pW1e, float* __restrict__ pGB, float* __restrict__ pSG,
    unsigned short* __restrict__ pW2t,
    unsigned short* __restrict__ W3th, unsigned short* __restrict__ W3tl,
    unsigned short* __restrict__ W4th, unsigned short* __restrict__ W4tl)
{
    const int tid = threadIdx.x;
    if (tid < 64) {
        pW1e[4 * tid + 0] = W1[tid];
        pW1e[4 * tid + 1] = W1[64 + tid];
        pW1e[4 * tid + 2] = W1[128 + tid];
        pW1e[4 * tid + 3] = b1[tid];
        pGB[2 * tid + 0] = g1[tid];
        pGB[2 * tid + 1] = be1[tid];
    }
    // S and Gram
    if (tid >= 64 && tid < 78) {
        const int t = tid - 64;
        auto wcomp = [&](int k, int i) -> float {
            return (i < 3) ? W1[i * 64 + k] : b1[k];
        };
        if (t < 4) {
            float s = 0.f;
            for (int k = 0; k < 64; k++) s += wcomp(k, t);
            pSG[t] = s;
        } else {
            const int pi[10] = {0,0,0,0,1,1,1,2,2,3};
            const int pj[10] = {0,1,2,3,1,2,3,2,3,3};
            int p = t - 4;
            float s = 0.f;
            for (int k = 0; k < 64; k++) s += wcomp(k, pi[p]) * wcomp(k, pj[p]);
            pSG[4 + p] = s;
        }
    }
    // W2^T bf16 padded
    for (int i = tid; i < 4096; i += 256) {
        int k = i >> 6, n = i & 63;
        pW2t[n * 72 + k] = f2bf(W2[i]);
    }
    for (int i = tid; i < 64 * 8; i += 256) {
        int n = i >> 3, k = 64 + (i & 7);
        pW2t[n * 72 + k] = 0;
    }
    // W3^T hi/lo
    for (int i = tid; i < 8192; i += 256) {
        int k = i >> 7, n = i & 127;
        float w = W3[k * 128 + n];
        unsigned short h = f2bf(w);
        W3th[n * 64 + k] = h;
        W3tl[n * 64 + k] = f2bf(w - bf2f(h));
    }
    // W4^T hi/lo
    for (int i = tid; i < 16384; i += 256) {
        int k = i >> 7, n = i & 127;
        float w = W4[k * 128 + n];
        unsigned short h = f2bf(w);
        W4th[n * 128 + k] = h;
        W4tl[n * 128 + k] = f2bf(w - bf2f(h));
    }
}

// ---------------------------------------------------------------------------
// K1: histogram
// ---------------------------------------------------------------------------
__global__ __launch_bounds__(256) void hist_kernel(const int* __restrict__ bidx,
                                                   unsigned* __restrict__ counts, int P) {
    int p0 = (blockIdx.x * 256 + threadIdx.x) * 4;
    if (p0 + 3 < P) {
        int4 n4 = *(const int4*)(bidx + p0);
        atomicAdd(&counts[n4.x], 1u);
        atomicAdd(&counts[n4.y], 1u);
        atomicAdd(&counts[n4.z], 1u);
        atomicAdd(&counts[n4.w], 1u);
    } else {
        for (int p = p0; p < P; p++) atomicAdd(&counts[bidx[p]], 1u);
    }
}

// ---------------------------------------------------------------------------
// K2: exclusive scan, uint4 loads + stores. N <= 65536.
// ---------------------------------------------------------------------------
__global__ __launch_bounds__(1024) void scan_kernel(const unsigned* __restrict__ counts,
                                                    unsigned* __restrict__ offsets,
                                                    unsigned* __restrict__ cursor, int N) {
    __shared__ unsigned waveTot[16];
    const int t = threadIdx.x;
    const int base = t * 64;
    unsigned local[64];
    unsigned s = 0;
    const bool fast = (base + 64 <= N) && ((N & 3) == 0);
    if (fast) {
        const uint4* c4 = (const uint4*)counts;
        for (int i = 0; i < 16; i++) {
            uint4 c = c4[t * 16 + i];
            local[4 * i + 0] = s; s += c.x;
            local[4 * i + 1] = s; s += c.y;
            local[4 * i + 2] = s; s += c.z;
            local[4 * i + 3] = s; s += c.w;
        }
    } else {
        for (int i = 0; i < 64; i++) {
            int idx = base + i;
            unsigned c = (idx < N) ? counts[idx] : 0u;
            local[i] = s;
            s += c;
        }
    }
    unsigned v = s;
    const int lane = t & 63;
    for (int off = 1; off < 64; off <<= 1) {
        unsigned u = __shfl_up(v, off);
        if (lane >= off) v += u;
    }
    if (lane == 63) waveTot[t >> 6] = v;
    __syncthreads();
    if (t == 0) {
        unsigned acc = 0;
        for (int w = 0; w < 16; w++) { unsigned tmp = waveTot[w]; waveTot[w] = acc; acc += tmp; }
    }
    __syncthreads();
    const unsigned chunkBase = waveTot[t >> 6] + (v - s);
    if (fast) {
        uint4* op = (uint4*)(offsets + base);
        uint4* cp = (uint4*)(cursor + base);
        for (int i = 0; i < 16; i++) {
            uint4 o = make_uint4(chunkBase + local[4 * i + 0], chunkBase + local[4 * i + 1],
                                 chunkBase + local[4 * i + 2], chunkBase + local[4 * i + 3]);
            op[i] = o;
            cp[i] = o;
        }
    } else {
        for (int i = 0; i < 64; i++) {
            int idx = base + i;
            if (idx < N) {
                unsigned o = chunkBase + local[i];
                offsets[idx] = o;
                cursor[idx]  = o;
            }
        }
    }
    if (t == 1023) offsets[N] = chunkBase + s;
}

// ---------------------------------------------------------------------------
// K3: scatter (x0,x1,x2,node) float4 into bucket order
// ---------------------------------------------------------------------------
__global__ __launch_bounds__(256) void scatter_kernel(const int* __restrict__ bidx,
                                                      const float* __restrict__ x,
                                                      unsigned* __restrict__ cursor,
                                                      float4* __restrict__ xb, int P) {
    int p = blockIdx.x * 256 + threadIdx.x;
    if (p < P) {
        int n = bidx[p];
        float x0 = x[3 * p + 0];
        float x1 = x[3 * p + 1];
        float x2 = x[3 * p + 2];
        unsigned pos = atomicAdd(&cursor[n], 1u);
        xb[pos] = make_float4(x0, x1, x2, __uint_as_float((unsigned)n));
    }
}

// ---------------------------------------------------------------------------
// K4: fused MLP1 + chunk-segmented max pool, MFMA GEMM.
// Phase 1: Gram-trick LN (mu/var from 4x4 quadratic form, zero LDS, params
// via uniform s_loads). Phase 2: per-wave 64x64x64 MFMA. Phase 3: segmented
// max; boundary nodes atomicMax.
// ---------------------------------------------------------------------------
__global__ __launch_bounds__(256, 2) void fused_mlp1_pool_kernel(
    const float4* __restrict__ xb, const unsigned* __restrict__ offsets,
    const float* __restrict__ pW1e, const float* __restrict__ pGB,
    const float* __restrict__ pSG, const unsigned short* __restrict__ pW2t,
    const float* __restrict__ b2,
    unsigned* __restrict__ segord, int P)
{
    __shared__ __align__(16) unsigned short sW2t[64 * 72];  // 9.2 KB
    __shared__ __align__(16) unsigned short sa[256 * 72];   // 36 KB
    __shared__ __align__(16) unsigned short shb[256 * 64];  // 32 KB
    __shared__ unsigned sn01[2];

    const int tid = threadIdx.x;
    // copy prepacked W2^T (flat, vectorized): 4608 shorts = 576 uint4
    {
        const uint4* src = (const uint4*)pW2t;
        uint4* dst = (uint4*)sW2t;
        for (int i = tid; i < 576; i += 256) dst[i] = src[i];
    }

    const int base = blockIdx.x * 256;
    const int row  = tid;
    const int pos  = base + row;
    const bool valid = (pos < P);

    float x0 = 0.f, x1 = 0.f, x2 = 0.f;
    if (valid) {
        float4 v = xb[pos];
        x0 = v.x; x1 = v.y; x2 = v.z;
        unsigned node = __float_as_uint(v.w);
        if (row == 0) sn01[0] = node;
        if (row == 255 || pos == P - 1) sn01[1] = node;
    }
    __syncthreads();

    // ---- Phase 1: layer-1 + LN + ReLU via Gram trick, bf16 -> sa
    {
        const float S0 = pSG[0], S1 = pSG[1], S2 = pSG[2], S3 = pSG[3];
        const float g00 = pSG[4], g01 = pSG[5], g02 = pSG[6], g03 = pSG[7];
        const float g11 = pSG[8], g12 = pSG[9], g13 = pSG[10];
        const float g22 = pSG[11], g23 = pSG[12], g33 = pSG[13];

        const float mu = fmaf(S0, x0, fmaf(S1, x1, fmaf(S2, x2, S3))) * (1.f / 64.f);
        float q = g33;
        q = fmaf(g00, x0 * x0, q);
        q = fmaf(g11, x1 * x1, q);
        q = fmaf(g22, x2 * x2, q);
        float c = fmaf(g01, x1, fmaf(g02, x2, g03));
        q = fmaf(2.f * x0, c, q);
        q = fmaf(2.f * x1, fmaf(g12, x2, g13), q);
        q = fmaf(2.f * x2, g23, q);
        float var = q * (1.f / 64.f) - mu * mu;
        var = var > 0.f ? var : 0.f;
        const float rs = rsqrtf(var + EPS_LN);
        const float r2 = -mu * rs;

        const float4* pw = (const float4*)pW1e;
        const float2* pg = (const float2*)pGB;
#pragma unroll
        for (int kb = 0; kb < 8; kb++) {
            bf16x8 v;
#pragma unroll
            for (int u = 0; u < 8; u++) {
                const int k = kb * 8 + u;
                float4 w = pw[k];           // uniform -> s_load
                float2 gb = pg[k];          // uniform -> s_load
                float y = fmaf(x0, w.x, fmaf(x1, w.y, fmaf(x2, w.z, w.w)));
                float tn = fmaf(y, rs, r2);
                float aa = fmaf(tn, gb.x, gb.y);
                aa = aa > 0.f ? aa : 0.f;
                v[u] = (short)f2bf(aa);
            }
            *reinterpret_cast<bf16x8*>(&sa[row * 72 + kb * 8]) = v;
        }
    }
    // no barrier: each wave MFMAs only its own 64 rows; sW2t covered by the
    // barrier above.

    // ---- Phase 2: h = a @ W2 + b2 via MFMA 16x16x32 bf16
    {
        const int wv   = tid >> 6;
        const int lane = tid & 63;
        const int m    = lane & 15;
        const int quad = lane >> 4;

        bf16x8 bfrag[4][2];
        float bc[4];
#pragma unroll
        for (int nt = 0; nt < 4; nt++) {
            bc[nt] = b2[nt * 16 + m];
#pragma unroll
            for (int s = 0; s < 2; s++)
                bfrag[nt][s] = *reinterpret_cast<const bf16x8*>(
                    &sW2t[(nt * 16 + m) * 72 + s * 32 + quad * 8]);
        }

#pragma unroll
        for (int rt = 0; rt < 4; rt++) {
            const int arow = wv * 64 + rt * 16 + m;
            bf16x8 af0 = *reinterpret_cast<const bf16x8*>(&sa[arow * 72 + quad * 8]);
            bf16x8 af1 = *reinterpret_cast<const bf16x8*>(&sa[arow * 72 + 32 + quad * 8]);
#pragma unroll
            for (int nt = 0; nt < 4; nt++) {
                f32x4 acc = {bc[nt], bc[nt], bc[nt], bc[nt]};
                acc = __builtin_amdgcn_mfma_f32_16x16x32_bf16(af0, bfrag[nt][0], acc, 0, 0, 0);
                acc = __builtin_amdgcn_mfma_f32_16x16x32_bf16(af1, bfrag[nt][1], acc, 0, 0, 0);
#pragma unroll
                for (int r = 0; r < 4; r++) {
                    const int orow = wv * 64 + rt * 16 + quad * 4 + r;
                    const int col  = nt * 16 + m;
                    shb[orow * 64 + (col ^ ((orow & 4) << 2))] = f2bf(acc[r]);
                }
            }
        }
    }
    __syncthreads();

    // ---- Phase 3: segmented max
    const int nValid = (P - base < 256) ? (P - base) : 256;
    if (nValid <= 0) return;
    const unsigned n0 = sn01[0];
    const unsigned n1 = sn01[1];
    const unsigned bEnd = (unsigned)(base + nValid);
    const int wave = tid >> 6;
    const int lane = tid & 63;

    for (unsigned n = n0 + (unsigned)wave; n <= n1; n += 4) {
        const unsigned s = offsets[n];
        const unsigned e = offsets[n + 1];
        int lo = (int)(s > (unsigned)base ? s : (unsigned)base) - base;
        int hi = (int)(e < bEnd ? e : bEnd) - base;
        if (hi <= lo) continue;
        float v = -3.402823466e38f;
        for (int r = lo; r < hi; r++) {
            v = fmaxf(v, bf2f(shb[r * 64 + (lane ^ ((r & 4) << 2))]));
        }
        const unsigned key = ordkey(v);
        unsigned* dst = &segord[(size_t)n * 64 + lane];
        if (s >= (unsigned)base && e <= bEnd) *dst = key;
        else atomicMax(dst, key);
    }
}

// ---------------------------------------------------------------------------
// K5: MLP2 fully in MFMA with split-bf16 (~fp32 accuracy).
// Block = 256 thr = 4 waves, 32 nodes/iter. Wave w owns j-tiles {2w,2w+1}.
// GEMM1: s (exactly bf16) @ (W3hi+W3lo). LN fp32. GEMM2:
// (uhi+ulo)@(W4hi+W4lo), lo*lo dropped. B-frags persistent in VGPRs.
// ---------------------------------------------------------------------------
__global__ __launch_bounds__(256) void mlp2_mfma_kernel(
    const unsigned* __restrict__ segord,
    const unsigned short* __restrict__ W3th, const unsigned short* __restrict__ W3tl,
    const unsigned short* __restrict__ W4th, const unsigned short* __restrict__ W4tl,
    const float* __restrict__ b3, const float* __restrict__ g2,
    const float* __restrict__ be2, const float* __restrict__ b4,
    float* __restrict__ out, int N)
{
    __shared__ __align__(16) unsigned short sa2[32 * 72];    // 4.6 KB
    __shared__ __align__(16) float st[32 * 132];             // 16.9 KB
    __shared__ __align__(16) unsigned short suh[32 * 136];   // 8.7 KB
    __shared__ __align__(16) unsigned short sul[32 * 136];   // 8.7 KB
    __shared__ float2 sred[32][8];
    __shared__ float sg2[128], sbe2[128];

    const int tid  = threadIdx.x;
    const int wv   = tid >> 6;
    const int lane = tid & 63;
    const int m    = lane & 15;
    const int quad = lane >> 4;

    if (tid < 128) { sg2[tid] = g2[tid]; sbe2[tid] = be2[tid]; }

    // persistent B-fragments + biases
    bf16x8 fw3h[2][2], fw3l[2][2];
    bf16x8 fw4h[2][4], fw4l[2][4];
    float bias3[2], bias4[2];
#pragma unroll
    for (int nti = 0; nti < 2; nti++) {
        const int nrow = (wv * 2 + nti) * 16 + m;
        bias3[nti] = b3[nrow];
        bias4[nti] = b4[nrow];
#pragma unroll
        for (int ks = 0; ks < 2; ks++) {
            fw3h[nti][ks] = *reinterpret_cast<const bf16x8*>(&W3th[nrow * 64 + ks * 32 + quad * 8]);
            fw3l[nti][ks] = *reinterpret_cast<const bf16x8*>(&W3tl[nrow * 64 + ks * 32 + quad * 8]);
        }
#pragma unroll
        for (int ks = 0; ks < 4; ks++) {
            fw4h[nti][ks] = *reinterpret_cast<const bf16x8*>(&W4th[nrow * 128 + ks * 32 + quad * 8]);
            fw4l[nti][ks] = *reinterpret_cast<const bf16x8*>(&W4tl[nrow * 128 + ks * 32 + quad * 8]);
        }
    }
    __syncthreads();

    for (int nb = blockIdx.x * 32; nb < N; nb += gridDim.x * 32) {
        // decode s -> sa2 (bf16, exact)
        {
            const int node = tid >> 3;
            const int k8   = (tid & 7) * 8;
            const uint4* sp = (const uint4*)&segord[(size_t)(nb + node) * 64 + k8];
            uint4 q0 = sp[0], q1 = sp[1];
            bf16x8 v;
            v[0] = (short)f2bf(decseg(q0.x));
            v[1] = (short)f2bf(decseg(q0.y));
            v[2] = (short)f2bf(decseg(q0.z));
            v[3] = (short)f2bf(decseg(q0.w));
            v[4] = (short)f2bf(decseg(q1.x));
            v[5] = (short)f2bf(decseg(q1.y));
            v[6] = (short)f2bf(decseg(q1.z));
            v[7] = (short)f2bf(decseg(q1.w));
            *reinterpret_cast<bf16x8*>(&sa2[node * 72 + k8]) = v;
        }
        __syncthreads();

        // GEMM1: t = s @ W3 + b3
#pragma unroll
        for (int mt = 0; mt < 2; mt++) {
            bf16x8 a0 = *reinterpret_cast<const bf16x8*>(&sa2[(mt * 16 + m) * 72 + quad * 8]);
            bf16x8 a1 = *reinterpret_cast<const bf16x8*>(&sa2[(mt * 16 + m) * 72 + 32 + quad * 8]);
#pragma unroll
            for (int nti = 0; nti < 2; nti++) {
                f32x4 acc = {bias3[nti], bias3[nti], bias3[nti], bias3[nti]};
                acc = __builtin_amdgcn_mfma_f32_16x16x32_bf16(a0, fw3h[nti][0], acc, 0, 0, 0);
                acc = __builtin_amdgcn_mfma_f32_16x16x32_bf16(a1, fw3h[nti][1], acc, 0, 0, 0);
                acc = __builtin_amdgcn_mfma_f32_16x16x32_bf16(a0, fw3l[nti][0], acc, 0, 0, 0);
                acc = __builtin_amdgcn_mfma_f32_16x16x32_bf16(a1, fw3l[nti][1], acc, 0, 0, 0);
#pragma unroll
                for (int r = 0; r < 4; r++)
                    st[(mt * 16 + quad * 4 + r) * 132 + (wv * 2 + nti) * 16 + m] = acc[r];
            }
        }
        __syncthreads();

        // LN + ReLU -> u hi/lo bf16
        {
            const int node = tid >> 3;
            const int seg  = tid & 7;
            const float4* rp = (const float4*)&st[node * 132 + seg * 16];
            float4 v0 = rp[0], v1 = rp[1], v2 = rp[2], v3 = rp[3];
            float s1 = v0.x + v0.y + v0.z + v0.w + v1.x + v1.y + v1.z + v1.w
                     + v2.x + v2.y + v2.z + v2.w + v3.x + v3.y + v3.z + v3.w;
            float s2 = 0.f;
            s2 = fmaf(v0.x, v0.x, s2); s2 = fmaf(v0.y, v0.y, s2); s2 = fmaf(v0.z, v0.z, s2); s2 = fmaf(v0.w, v0.w, s2);
            s2 = fmaf(v1.x, v1.x, s2); s2 = fmaf(v1.y, v1.y, s2); s2 = fmaf(v1.z, v1.z, s2); s2 = fmaf(v1.w, v1.w, s2);
            s2 = fmaf(v2.x, v2.x, s2); s2 = fmaf(v2.y, v2.y, s2); s2 = fmaf(v2.z, v2.z, s2); s2 = fmaf(v2.w, v2.w, s2);
            s2 = fmaf(v3.x, v3.x, s2); s2 = fmaf(v3.y, v3.y, s2); s2 = fmaf(v3.z, v3.z, s2); s2 = fmaf(v3.w, v3.w, s2);
            sred[node][seg] = make_float2(s1, s2);
            __syncthreads();

            float t1 = 0.f, t2 = 0.f;
#pragma unroll
            for (int i = 0; i < 8; i++) { float2 r = sred[node][i]; t1 += r.x; t2 += r.y; }
            const float mu  = t1 * (1.f / 128.f);
            float var = t2 * (1.f / 128.f) - mu * mu;
            var = var > 0.f ? var : 0.f;
            const float rsd = rsqrtf(var + EPS_LN);

            float tv[16] = {v0.x, v0.y, v0.z, v0.w, v1.x, v1.y, v1.z, v1.w,
                            v2.x, v2.y, v2.z, v2.w, v3.x, v3.y, v3.z, v3.w};
            bf16x8 vh[2], vl[2];
#pragma unroll
            for (int i = 0; i < 16; i++) {
                const int j = seg * 16 + i;
                float u = fmaf((tv[i] - mu) * rsd, sg2[j], sbe2[j]);
                u = u > 0.f ? u : 0.f;
                unsigned short uh = f2bf(u);
                unsigned short ul = f2bf(u - bf2f(uh));
                vh[i >> 3][i & 7] = (short)uh;
                vl[i >> 3][i & 7] = (short)ul;
            }
            *reinterpret_cast<bf16x8*>(&suh[node * 136 + seg * 16])     = vh[0];
            *reinterpret_cast<bf16x8*>(&suh[node * 136 + seg * 16 + 8]) = vh[1];
            *reinterpret_cast<bf16x8*>(&sul[node * 136 + seg * 16])     = vl[0];
            *reinterpret_cast<bf16x8*>(&sul[node * 136 + seg * 16 + 8]) = vl[1];
        }
        __syncthreads();

        // GEMM2: out = u @ W4 + b4
#pragma unroll
        for (int mt = 0; mt < 2; mt++) {
            bf16x8 ah[4], al[4];
#pragma unroll
            for (int ks = 0; ks < 4; ks++) {
                ah[ks] = *reinterpret_cast<const bf16x8*>(&suh[(mt * 16 + m) * 136 + ks * 32 + quad * 8]);
                al[ks] = *reinterpret_cast<const bf16x8*>(&sul[(mt * 16 + m) * 136 + ks * 32 + quad * 8]);
            }
#pragma unroll
            for (int nti = 0; nti < 2; nti++) {
                f32x4 acc = {bias4[nti], bias4[nti], bias4[nti], bias4[nti]};
#pragma unroll
                for (int ks = 0; ks < 4; ks++) {
                    acc = __builtin_amdgcn_mfma_f32_16x16x32_bf16(ah[ks], fw4h[nti][ks], acc, 0, 0, 0);
                    acc = __builtin_amdgcn_mfma_f32_16x16x32_bf16(al[ks], fw4h[nti][ks], acc, 0, 0, 0);
                    acc = __builtin_amdgcn_mfma_f32_16x16x32_bf16(ah[ks], fw4l[nti][ks], acc, 0, 0, 0);
                }
#pragma unroll
                for (int r = 0; r < 4; r++) {
                    const int node = nb + mt * 16 + quad * 4 + r;
                    if (node < N)
                        out[(size_t)node * 128 + (wv * 2 + nti) * 16 + m] = acc[r];
                }
            }
        }
        __syncthreads();
    }
}

extern "C" void kernel_launch(void* const* d_in, const int* in_sizes, int n_in,
                              void* d_out, int out_size, void* d_ws, size_t ws_size,
                              hipStream_t stream) {
    const float* x    = (const float*)d_in[0];
    const int*   bidx = (const int*)d_in[1];
    const float* W1  = (const float*)d_in[3];
    const float* b1  = (const float*)d_in[4];
    const float* g1  = (const float*)d_in[5];
    const float* be1 = (const float*)d_in[6];
    const float* W2  = (const float*)d_in[7];
    const float* b2  = (const float*)d_in[8];
    const float* W3  = (const float*)d_in[9];
    const float* b3  = (const float*)d_in[10];
    const float* g2  = (const float*)d_in[11];
    const float* be2 = (const float*)d_in[12];
    const float* W4  = (const float*)d_in[13];
    const float* b4  = (const float*)d_in[14];

    const int P = in_sizes[0] / 3;
    const int N = out_size / 128;

    uintptr_t w = (uintptr_t)d_ws;
    auto align = [](uintptr_t v) { return (v + 255) & ~(uintptr_t)255; };
    unsigned* counts  = (unsigned*)align(w);        w = (uintptr_t)(counts  + N);
    unsigned* offsets = (unsigned*)align(w);        w = (uintptr_t)(offsets + N + 1);
    unsigned* cursor  = (unsigned*)align(w);        w = (uintptr_t)(cursor  + N);
    float4*   xb      = (float4*)align(w);          w = (uintptr_t)(xb      + P);
    unsigned* segord  = (unsigned*)align(w);        w = (uintptr_t)(segord  + (size_t)N * 64);
    float*    pW1e    = (float*)align(w);           w = (uintptr_t)(pW1e    + 256);
    float*    pGB     = (float*)align(w);           w = (uintptr_t)(pGB     + 128);
    float*    pSG     = (float*)align(w);           w = (uintptr_t)(pSG     + 16);
    unsigned short* pW2t = (unsigned short*)align(w); w = (uintptr_t)(pW2t + 64 * 72);
    unsigned short* W3th = (unsigned short*)align(w); w = (uintptr_t)(W3th + 128 * 64);
    unsigned short* W3tl = (unsigned short*)align(w); w = (uintptr_t)(W3tl + 128 * 64);
    unsigned short* W4th = (unsigned short*)align(w); w = (uintptr_t)(W4th + 128 * 128);
    unsigned short* W4tl = (unsigned short*)align(w); w = (uintptr_t)(W4tl + 128 * 128);

    hipMemsetAsync(counts, 0, (size_t)N * sizeof(unsigned), stream);
    hipMemsetAsync(segord, 0, (size_t)N * 64 * sizeof(unsigned), stream);

    prep_kernel<<<1, 256, 0, stream>>>(W1, b1, g1, be1, W2, W3, W4,
                                       pW1e, pGB, pSG, pW2t, W3th, W3tl, W4th, W4tl);

    hist_kernel<<<(P + 1023) / 1024, 256, 0, stream>>>(bidx, counts, P);
    scan_kernel<<<1, 1024, 0, stream>>>(counts, offsets, cursor, N);
    scatter_kernel<<<(P + 255) / 256, 256, 0, stream>>>(bidx, x, cursor, xb, P);

    fused_mlp1_pool_kernel<<<(P + 255) / 256, 256, 0, stream>>>(
        xb, offsets, pW1e, pGB, pSG, pW2t, b2, segord, P);

    mlp2_mfma_kernel<<<512, 256, 0, stream>>>(
        segord, W3th, W3tl, W4th, W4tl, b3, g2, be2, b4, (float*)d_out, N);
}

// Round 7
// 405.613 us; speedup vs baseline: 14.5232x; 1.4961x over previous
//
#include <hip/hip_runtime.h>
#include <hip/hip_bf16.h>
#include <math.h>

#define EPS_LN 1e-5f

typedef __attribute__((ext_vector_type(8))) short bf16x8;
typedef __attribute__((ext_vector_type(4))) float f32x4;

__device__ __forceinline__ unsigned ordkey(float f) {
    unsigned u = __float_as_uint(f);
    return (u & 0x80000000u) ? ~u : (u | 0x80000000u);
}
__device__ __forceinline__ float orddecode(unsigned o) {
    unsigned u = (o & 0x80000000u) ? (o & 0x7FFFFFFFu) : ~o;
    return __uint_as_float(u);
}
__device__ __forceinline__ unsigned short f2bf(float f) {
    __hip_bfloat16 h = __float2bfloat16(f);
    return *reinterpret_cast<unsigned short*>(&h);
}
__device__ __forceinline__ float bf2f(unsigned short u) {
    return __uint_as_float(((unsigned)u) << 16);
}
__device__ __forceinline__ float decseg(unsigned o) { return o ? orddecode(o) : 0.f; }

// ---------------------------------------------------------------------------
// K0: prep — pack params once per call (unchanged from R6).
// ---------------------------------------------------------------------------
__global__ __launch_bounds__(256) void prep_kernel(
    const float* __restrict__ W1, const float* __restrict__ b1,
    const float* __restrict__ g1, const float* __restrict__ be1,
    const float* __restrict__ W2,
    const float* __restrict__ W3, const float* __restrict__ W4,
    float* __restrict__ pW1e, float* __restrict__ pGB, float* __restrict__ pSG,
    unsigned short* __restrict__ pW2t,
    unsigned short* __restrict__ W3th, unsigned short* __restrict__ W3tl,
    unsigned short* __restrict__ W4th, unsigned short* __restrict__ W4tl)
{
    const int tid = threadIdx.x;
    if (tid < 64) {
        pW1e[4 * tid + 0] = W1[tid];
        pW1e[4 * tid + 1] = W1[64 + tid];
        pW1e[4 * tid + 2] = W1[128 + tid];
        pW1e[4 * tid + 3] = b1[tid];
        pGB[2 * tid + 0] = g1[tid];
        pGB[2 * tid + 1] = be1[tid];
    }
    if (tid >= 64 && tid < 78) {
        const int t = tid - 64;
        auto wcomp = [&](int k, int i) -> float {
            return (i < 3) ? W1[i * 64 + k] : b1[k];
        };
        if (t < 4) {
            float s = 0.f;
            for (int k = 0; k < 64; k++) s += wcomp(k, t);
            pSG[t] = s;
        } else {
            const int pi[10] = {0,0,0,0,1,1,1,2,2,3};
            const int pj[10] = {0,1,2,3,1,2,3,2,3,3};
            int p = t - 4;
            float s = 0.f;
            for (int k = 0; k < 64; k++) s += wcomp(k, pi[p]) * wcomp(k, pj[p]);
            pSG[4 + p] = s;
        }
    }
    for (int i = tid; i < 4096; i += 256) {
        int k = i >> 6, n = i & 63;
        pW2t[n * 72 + k] = f2bf(W2[i]);
    }
    for (int i = tid; i < 64 * 8; i += 256) {
        int n = i >> 3, k = 64 + (i & 7);
        pW2t[n * 72 + k] = 0;
    }
    for (int i = tid; i < 8192; i += 256) {
        int k = i >> 7, n = i & 127;
        float w = W3[k * 128 + n];
        unsigned short h = f2bf(w);
        W3th[n * 64 + k] = h;
        W3tl[n * 64 + k] = f2bf(w - bf2f(h));
    }
    for (int i = tid; i < 16384; i += 256) {
        int k = i >> 7, n = i & 127;
        float w = W4[k * 128 + n];
        unsigned short h = f2bf(w);
        W4th[n * 128 + k] = h;
        W4tl[n * 128 + k] = f2bf(w - bf2f(h));
    }
}

// ---------------------------------------------------------------------------
// S1: partition counts (node>>8), 4096 points/block, LDS hist ->
// one global atomicAdd per (block, nonempty bin).  131K atomics vs 2M.
// ---------------------------------------------------------------------------
__global__ __launch_bounds__(256) void part_count_kernel(const int* __restrict__ bidx,
                                                         unsigned* __restrict__ partCount,
                                                         int P) {
    __shared__ unsigned hist[256];
    const int tid = threadIdx.x;
    hist[tid] = 0;
    __syncthreads();
    const int base = blockIdx.x * 4096;
#pragma unroll
    for (int j = 0; j < 4; j++) {
        const int p0 = base + j * 1024 + tid * 4;
        if (p0 + 3 < P) {
            int4 n4 = *(const int4*)(bidx + p0);
            atomicAdd(&hist[((unsigned)n4.x) >> 8], 1u);
            atomicAdd(&hist[((unsigned)n4.y) >> 8], 1u);
            atomicAdd(&hist[((unsigned)n4.z) >> 8], 1u);
            atomicAdd(&hist[((unsigned)n4.w) >> 8], 1u);
        } else {
            for (int p = p0; p < P && p < p0 + 4; p++)
                atomicAdd(&hist[((unsigned)bidx[p]) >> 8], 1u);
        }
    }
    __syncthreads();
    if (hist[tid]) atomicAdd(&partCount[tid], hist[tid]);
}

// ---------------------------------------------------------------------------
// S2: scan partition counts -> partBase[nparts+1], partCursor. nparts <= 256.
// ---------------------------------------------------------------------------
__global__ __launch_bounds__(256) void part_scan_kernel(const unsigned* __restrict__ partCount,
                                                        unsigned* __restrict__ partBase,
                                                        unsigned* __restrict__ partCursor,
                                                        int nparts) {
    __shared__ unsigned wtot[4];
    const int t = threadIdx.x;
    const unsigned c = (t < nparts) ? partCount[t] : 0u;
    unsigned v = c;
    const int lane = t & 63;
    for (int off = 1; off < 64; off <<= 1) {
        unsigned u = __shfl_up(v, off);
        if (lane >= off) v += u;
    }
    if (lane == 63) wtot[t >> 6] = v;
    __syncthreads();
    if (t == 0) {
        unsigned a = 0;
        for (int w = 0; w < 4; w++) { unsigned tmp = wtot[w]; wtot[w] = a; a += tmp; }
    }
    __syncthreads();
    const unsigned excl = wtot[t >> 6] + v - c;
    if (t < nparts) { partBase[t] = excl; partCursor[t] = excl; }
    if (t == nparts - 1) partBase[nparts] = excl + c;
}

// ---------------------------------------------------------------------------
// S3: scatter (x,node) float4 records into partition-grouped xb.
// LDS hist -> one global atomicAdd per (block,bin) to reserve a range,
// then LDS-cursor assignment. Writes stream into 256 regions.
// ---------------------------------------------------------------------------
__global__ __launch_bounds__(256) void part_scatter_kernel(const int* __restrict__ bidx,
                                                           const float* __restrict__ x,
                                                           unsigned* __restrict__ partCursor,
                                                           float4* __restrict__ xb, int P) {
    __shared__ unsigned hist[256];
    __shared__ unsigned cur[256];
    const int tid = threadIdx.x;
    hist[tid] = 0;
    __syncthreads();
    const int base = blockIdx.x * 4096;

    unsigned nodes[16];
#pragma unroll
    for (int j = 0; j < 4; j++) {
        const int p0 = base + j * 1024 + tid * 4;
        if (p0 + 3 < P) {
            int4 n4 = *(const int4*)(bidx + p0);
            nodes[4 * j + 0] = (unsigned)n4.x;
            nodes[4 * j + 1] = (unsigned)n4.y;
            nodes[4 * j + 2] = (unsigned)n4.z;
            nodes[4 * j + 3] = (unsigned)n4.w;
            atomicAdd(&hist[nodes[4 * j + 0] >> 8], 1u);
            atomicAdd(&hist[nodes[4 * j + 1] >> 8], 1u);
            atomicAdd(&hist[nodes[4 * j + 2] >> 8], 1u);
            atomicAdd(&hist[nodes[4 * j + 3] >> 8], 1u);
        } else {
            for (int u = 0; u < 4; u++) {
                const int p = p0 + u;
                if (p < P) {
                    nodes[4 * j + u] = (unsigned)bidx[p];
                    atomicAdd(&hist[nodes[4 * j + u] >> 8], 1u);
                } else nodes[4 * j + u] = 0u;
            }
        }
    }
    __syncthreads();
    if (hist[tid]) cur[tid] = atomicAdd(&partCursor[tid], hist[tid]);
    __syncthreads();

#pragma unroll
    for (int j = 0; j < 4; j++) {
        const int p0 = base + j * 1024 + tid * 4;
        if (p0 + 3 < P) {
            const float4* xv = (const float4*)(x + 3 * (size_t)p0);
            float4 a = xv[0], b = xv[1], c = xv[2];
            const float xs[12] = {a.x, a.y, a.z, a.w, b.x, b.y, b.z, b.w,
                                  c.x, c.y, c.z, c.w};
#pragma unroll
            for (int u = 0; u < 4; u++) {
                const unsigned n = nodes[4 * j + u];
                const unsigned dst = atomicAdd(&cur[n >> 8], 1u);
                xb[dst] = make_float4(xs[3 * u], xs[3 * u + 1], xs[3 * u + 2],
                                      __uint_as_float(n));
            }
        } else {
            for (int u = 0; u < 4; u++) {
                const int p = p0 + u;
                if (p < P) {
                    const unsigned n = nodes[4 * j + u];
                    const unsigned dst = atomicAdd(&cur[n >> 8], 1u);
                    xb[dst] = make_float4(x[3 * p], x[3 * p + 1], x[3 * p + 2],
                                          __uint_as_float(n));
                }
            }
        }
    }
}

// ---------------------------------------------------------------------------
// S4: per-partition CSR + in-place node-sort. One block per partition
// (~8.2K recs, Binomial(2M,1/256): 9216-cap is >11 sigma). Stages the whole
// partition in LDS (147.5 KB), LDS hist over node&255, scan, writes global
// offsets and node-sorted xb back in place.
// ---------------------------------------------------------------------------
__global__ __launch_bounds__(256, 1) void part_csr_kernel(const unsigned* __restrict__ partBase,
                                                          unsigned* __restrict__ offsets,
                                                          float4* __restrict__ xb, int N) {
    __shared__ float4 stage[9216];       // 147.5 KB
    __shared__ unsigned hist[256], cur[256], wtot[4];
    const int tid = threadIdx.x;
    const int p = blockIdx.x;
    const unsigned start = partBase[p];
    const unsigned end   = partBase[p + 1];
    const unsigned cnt0  = end - start;
    const unsigned cnt   = cnt0 < 9216u ? cnt0 : 9216u;   // overflow prob ~1e-30

    hist[tid] = 0;
    __syncthreads();
    for (unsigned k = tid; k < cnt; k += 256) {
        float4 r = xb[start + k];
        stage[k] = r;
        atomicAdd(&hist[__float_as_uint(r.w) & 255u], 1u);
    }
    __syncthreads();

    // exclusive scan of hist
    const unsigned c = hist[tid];
    unsigned v = c;
    const int lane = tid & 63;
    for (int off = 1; off < 64; off <<= 1) {
        unsigned u = __shfl_up(v, off);
        if (lane >= off) v += u;
    }
    if (lane == 63) wtot[tid >> 6] = v;
    __syncthreads();
    if (tid == 0) {
        unsigned a = 0;
        for (int w = 0; w < 4; w++) { unsigned tmp = wtot[w]; wtot[w] = a; a += tmp; }
    }
    __syncthreads();
    const unsigned excl = wtot[tid >> 6] + v - c;

    const int node = p * 256 + tid;
    if (node < N) offsets[node] = start + excl;
    if (node == N - 1) offsets[N] = start + excl + c;
    cur[tid] = start + excl;
    __syncthreads();

    for (unsigned k = tid; k < cnt; k += 256) {
        float4 r = stage[k];
        const unsigned dst = atomicAdd(&cur[__float_as_uint(r.w) & 255u], 1u);
        xb[dst] = r;
    }
}

// ---------------------------------------------------------------------------
// K4: fused MLP1 + chunk-segmented max pool, MFMA GEMM (unchanged from R6).
// ---------------------------------------------------------------------------
__global__ __launch_bounds__(256, 2) void fused_mlp1_pool_kernel(
    const float4* __restrict__ xb, const unsigned* __restrict__ offsets,
    const float* __restrict__ pW1e, const float* __restrict__ pGB,
    const float* __restrict__ pSG, const unsigned short* __restrict__ pW2t,
    const float* __restrict__ b2,
    unsigned* __restrict__ segord, int P)
{
    __shared__ __align__(16) unsigned short sW2t[64 * 72];
    __shared__ __align__(16) unsigned short sa[256 * 72];
    __shared__ __align__(16) unsigned short shb[256 * 64];
    __shared__ unsigned sn01[2];

    const int tid = threadIdx.x;
    {
        const uint4* src = (const uint4*)pW2t;
        uint4* dst = (uint4*)sW2t;
        for (int i = tid; i < 576; i += 256) dst[i] = src[i];
    }

    const int base = blockIdx.x * 256;
    const int row  = tid;
    const int pos  = base + row;
    const bool valid = (pos < P);

    float x0 = 0.f, x1 = 0.f, x2 = 0.f;
    if (valid) {
        float4 v = xb[pos];
        x0 = v.x; x1 = v.y; x2 = v.z;
        unsigned node = __float_as_uint(v.w);
        if (row == 0) sn01[0] = node;
        if (row == 255 || pos == P - 1) sn01[1] = node;
    }
    __syncthreads();

    {
        const float S0 = pSG[0], S1 = pSG[1], S2 = pSG[2], S3 = pSG[3];
        const float g00 = pSG[4], g01 = pSG[5], g02 = pSG[6], g03 = pSG[7];
        const float g11 = pSG[8], g12 = pSG[9], g13 = pSG[10];
        const float g22 = pSG[11], g23 = pSG[12], g33 = pSG[13];

        const float mu = fmaf(S0, x0, fmaf(S1, x1, fmaf(S2, x2, S3))) * (1.f / 64.f);
        float q = g33;
        q = fmaf(g00, x0 * x0, q);
        q = fmaf(g11, x1 * x1, q);
        q = fmaf(g22, x2 * x2, q);
        float c = fmaf(g01, x1, fmaf(g02, x2, g03));
        q = fmaf(2.f * x0, c, q);
        q = fmaf(2.f * x1, fmaf(g12, x2, g13), q);
        q = fmaf(2.f * x2, g23, q);
        float var = q * (1.f / 64.f) - mu * mu;
        var = var > 0.f ? var : 0.f;
        const float rs = rsqrtf(var + EPS_LN);
        const float r2 = -mu * rs;

        const float4* pw = (const float4*)pW1e;
        const float2* pg = (const float2*)pGB;
#pragma unroll
        for (int kb = 0; kb < 8; kb++) {
            bf16x8 v;
#pragma unroll
            for (int u = 0; u < 8; u++) {
                const int k = kb * 8 + u;
                float4 w = pw[k];
                float2 gb = pg[k];
                float y = fmaf(x0, w.x, fmaf(x1, w.y, fmaf(x2, w.z, w.w)));
                float tn = fmaf(y, rs, r2);
                float aa = fmaf(tn, gb.x, gb.y);
                aa = aa > 0.f ? aa : 0.f;
                v[u] = (short)f2bf(aa);
            }
            *reinterpret_cast<bf16x8*>(&sa[row * 72 + kb * 8]) = v;
        }
    }

    {
        const int wv   = tid >> 6;
        const int lane = tid & 63;
        const int m    = lane & 15;
        const int quad = lane >> 4;

        bf16x8 bfrag[4][2];
        float bc[4];
#pragma unroll
        for (int nt = 0; nt < 4; nt++) {
            bc[nt] = b2[nt * 16 + m];
#pragma unroll
            for (int s = 0; s < 2; s++)
                bfrag[nt][s] = *reinterpret_cast<const bf16x8*>(
                    &sW2t[(nt * 16 + m) * 72 + s * 32 + quad * 8]);
        }

#pragma unroll
        for (int rt = 0; rt < 4; rt++) {
            const int arow = wv * 64 + rt * 16 + m;
            bf16x8 af0 = *reinterpret_cast<const bf16x8*>(&sa[arow * 72 + quad * 8]);
            bf16x8 af1 = *reinterpret_cast<const bf16x8*>(&sa[arow * 72 + 32 + quad * 8]);
#pragma unroll
            for (int nt = 0; nt < 4; nt++) {
                f32x4 acc = {bc[nt], bc[nt], bc[nt], bc[nt]};
                acc = __builtin_amdgcn_mfma_f32_16x16x32_bf16(af0, bfrag[nt][0], acc, 0, 0, 0);
                acc = __builtin_amdgcn_mfma_f32_16x16x32_bf16(af1, bfrag[nt][1], acc, 0, 0, 0);
#pragma unroll
                for (int r = 0; r < 4; r++) {
                    const int orow = wv * 64 + rt * 16 + quad * 4 + r;
                    const int col  = nt * 16 + m;
                    shb[orow * 64 + (col ^ ((orow & 4) << 2))] = f2bf(acc[r]);
                }
            }
        }
    }
    __syncthreads();

    const int nValid = (P - base < 256) ? (P - base) : 256;
    if (nValid <= 0) return;
    const unsigned n0 = sn01[0];
    const unsigned n1 = sn01[1];
    const unsigned bEnd = (unsigned)(base + nValid);
    const int wave = tid >> 6;
    const int lane = tid & 63;

    for (unsigned n = n0 + (unsigned)wave; n <= n1; n += 4) {
        const unsigned s = offsets[n];
        const unsigned e = offsets[n + 1];
        int lo = (int)(s > (unsigned)base ? s : (unsigned)base) - base;
        int hi = (int)(e < bEnd ? e : bEnd) - base;
        if (hi <= lo) continue;
        float v = -3.402823466e38f;
        for (int r = lo; r < hi; r++) {
            v = fmaxf(v, bf2f(shb[r * 64 + (lane ^ ((r & 4) << 2))]));
        }
        const unsigned key = ordkey(v);
        unsigned* dst = &segord[(size_t)n * 64 + lane];
        if (s >= (unsigned)base && e <= bEnd) *dst = key;
        else atomicMax(dst, key);
    }
}

// ---------------------------------------------------------------------------
// K5: MLP2 fully in MFMA with split-bf16 (unchanged from R6).
// ---------------------------------------------------------------------------
__global__ __launch_bounds__(256) void mlp2_mfma_kernel(
    const unsigned* __restrict__ segord,
    const unsigned short* __restrict__ W3th, const unsigned short* __restrict__ W3tl,
    const unsigned short* __restrict__ W4th, const unsigned short* __restrict__ W4tl,
    const float* __restrict__ b3, const float* __restrict__ g2,
    const float* __restrict__ be2, const float* __restrict__ b4,
    float* __restrict__ out, int N)
{
    __shared__ __align__(16) unsigned short sa2[32 * 72];
    __shared__ __align__(16) float st[32 * 132];
    __shared__ __align__(16) unsigned short suh[32 * 136];
    __shared__ __align__(16) unsigned short sul[32 * 136];
    __shared__ float2 sred[32][8];
    __shared__ float sg2[128], sbe2[128];

    const int tid  = threadIdx.x;
    const int wv   = tid >> 6;
    const int lane = tid & 63;
    const int m    = lane & 15;
    const int quad = lane >> 4;

    if (tid < 128) { sg2[tid] = g2[tid]; sbe2[tid] = be2[tid]; }

    bf16x8 fw3h[2][2], fw3l[2][2];
    bf16x8 fw4h[2][4], fw4l[2][4];
    float bias3[2], bias4[2];
#pragma unroll
    for (int nti = 0; nti < 2; nti++) {
        const int nrow = (wv * 2 + nti) * 16 + m;
        bias3[nti] = b3[nrow];
        bias4[nti] = b4[nrow];
#pragma unroll
        for (int ks = 0; ks < 2; ks++) {
            fw3h[nti][ks] = *reinterpret_cast<const bf16x8*>(&W3th[nrow * 64 + ks * 32 + quad * 8]);
            fw3l[nti][ks] = *reinterpret_cast<const bf16x8*>(&W3tl[nrow * 64 + ks * 32 + quad * 8]);
        }
#pragma unroll
        for (int ks = 0; ks < 4; ks++) {
            fw4h[nti][ks] = *reinterpret_cast<const bf16x8*>(&W4th[nrow * 128 + ks * 32 + quad * 8]);
            fw4l[nti][ks] = *reinterpret_cast<const bf16x8*>(&W4tl[nrow * 128 + ks * 32 + quad * 8]);
        }
    }
    __syncthreads();

    for (int nb = blockIdx.x * 32; nb < N; nb += gridDim.x * 32) {
        {
            const int node = tid >> 3;
            const int k8   = (tid & 7) * 8;
            const uint4* sp = (const uint4*)&segord[(size_t)(nb + node) * 64 + k8];
            uint4 q0 = sp[0], q1 = sp[1];
            bf16x8 v;
            v[0] = (short)f2bf(decseg(q0.x));
            v[1] = (short)f2bf(decseg(q0.y));
            v[2] = (short)f2bf(decseg(q0.z));
            v[3] = (short)f2bf(decseg(q0.w));
            v[4] = (short)f2bf(decseg(q1.x));
            v[5] = (short)f2bf(decseg(q1.y));
            v[6] = (short)f2bf(decseg(q1.z));
            v[7] = (short)f2bf(decseg(q1.w));
            *reinterpret_cast<bf16x8*>(&sa2[node * 72 + k8]) = v;
        }
        __syncthreads();

#pragma unroll
        for (int mt = 0; mt < 2; mt++) {
            bf16x8 a0 = *reinterpret_cast<const bf16x8*>(&sa2[(mt * 16 + m) * 72 + quad * 8]);
            bf16x8 a1 = *reinterpret_cast<const bf16x8*>(&sa2[(mt * 16 + m) * 72 + 32 + quad * 8]);
#pragma unroll
            for (int nti = 0; nti < 2; nti++) {
                f32x4 acc = {bias3[nti], bias3[nti], bias3[nti], bias3[nti]};
                acc = __builtin_amdgcn_mfma_f32_16x16x32_bf16(a0, fw3h[nti][0], acc, 0, 0, 0);
                acc = __builtin_amdgcn_mfma_f32_16x16x32_bf16(a1, fw3h[nti][1], acc, 0, 0, 0);
                acc = __builtin_amdgcn_mfma_f32_16x16x32_bf16(a0, fw3l[nti][0], acc, 0, 0, 0);
                acc = __builtin_amdgcn_mfma_f32_16x16x32_bf16(a1, fw3l[nti][1], acc, 0, 0, 0);
#pragma unroll
                for (int r = 0; r < 4; r++)
                    st[(mt * 16 + quad * 4 + r) * 132 + (wv * 2 + nti) * 16 + m] = acc[r];
            }
        }
        __syncthreads();

        {
            const int node = tid >> 3;
            const int seg  = tid & 7;
            const float4* rp = (const float4*)&st[node * 132 + seg * 16];
            float4 v0 = rp[0], v1 = rp[1], v2 = rp[2], v3 = rp[3];
            float s1 = v0.x + v0.y + v0.z + v0.w + v1.x + v1.y + v1.z + v1.w
                     + v2.x + v2.y + v2.z + v2.w + v3.x + v3.y + v3.z + v3.w;
            float s2 = 0.f;
            s2 = fmaf(v0.x, v0.x, s2); s2 = fmaf(v0.y, v0.y, s2); s2 = fmaf(v0.z, v0.z, s2); s2 = fmaf(v0.w, v0.w, s2);
            s2 = fmaf(v1.x, v1.x, s2); s2 = fmaf(v1.y, v1.y, s2); s2 = fmaf(v1.z, v1.z, s2); s2 = fmaf(v1.w, v1.w, s2);
            s2 = fmaf(v2.x, v2.x, s2); s2 = fmaf(v2.y, v2.y, s2); s2 = fmaf(v2.z, v2.z, s2); s2 = fmaf(v2.w, v2.w, s2);
            s2 = fmaf(v3.x, v3.x, s2); s2 = fmaf(v3.y, v3.y, s2); s2 = fmaf(v3.z, v3.z, s2); s2 = fmaf(v3.w, v3.w, s2);
            sred[node][seg] = make_float2(s1, s2);
            __syncthreads();

            float t1 = 0.f, t2 = 0.f;
#pragma unroll
            for (int i = 0; i < 8; i++) { float2 r = sred[node][i]; t1 += r.x; t2 += r.y; }
            const float mu  = t1 * (1.f / 128.f);
            float var = t2 * (1.f / 128.f) - mu * mu;
            var = var > 0.f ? var : 0.f;
            const float rsd = rsqrtf(var + EPS_LN);

            float tv[16] = {v0.x, v0.y, v0.z, v0.w, v1.x, v1.y, v1.z, v1.w,
                            v2.x, v2.y, v2.z, v2.w, v3.x, v3.y, v3.z, v3.w};
            bf16x8 vh[2], vl[2];
#pragma unroll
            for (int i = 0; i < 16; i++) {
                const int j = seg * 16 + i;
                float u = fmaf((tv[i] - mu) * rsd, sg2[j], sbe2[j]);
                u = u > 0.f ? u : 0.f;
                unsigned short uh = f2bf(u);
                unsigned short ul = f2bf(u - bf2f(uh));
                vh[i >> 3][i & 7] = (short)uh;
                vl[i >> 3][i & 7] = (short)ul;
            }
            *reinterpret_cast<bf16x8*>(&suh[node * 136 + seg * 16])     = vh[0];
            *reinterpret_cast<bf16x8*>(&suh[node * 136 + seg * 16 + 8]) = vh[1];
            *reinterpret_cast<bf16x8*>(&sul[node * 136 + seg * 16])     = vl[0];
            *reinterpret_cast<bf16x8*>(&sul[node * 136 + seg * 16 + 8]) = vl[1];
        }
        __syncthreads();

#pragma unroll
        for (int mt = 0; mt < 2; mt++) {
            bf16x8 ah[4], al[4];
#pragma unroll
            for (int ks = 0; ks < 4; ks++) {
                ah[ks] = *reinterpret_cast<const bf16x8*>(&suh[(mt * 16 + m) * 136 + ks * 32 + quad * 8]);
                al[ks] = *reinterpret_cast<const bf16x8*>(&sul[(mt * 16 + m) * 136 + ks * 32 + quad * 8]);
            }
#pragma unroll
            for (int nti = 0; nti < 2; nti++) {
                f32x4 acc = {bias4[nti], bias4[nti], bias4[nti], bias4[nti]};
#pragma unroll
                for (int ks = 0; ks < 4; ks++) {
                    acc = __builtin_amdgcn_mfma_f32_16x16x32_bf16(ah[ks], fw4h[nti][ks], acc, 0, 0, 0);
                    acc = __builtin_amdgcn_mfma_f32_16x16x32_bf16(al[ks], fw4h[nti][ks], acc, 0, 0, 0);
                    acc = __builtin_amdgcn_mfma_f32_16x16x32_bf16(ah[ks], fw4l[nti][ks], acc, 0, 0, 0);
                }
#pragma unroll
                for (int r = 0; r < 4; r++) {
                    const int node = nb + mt * 16 + quad * 4 + r;
                    if (node < N)
                        out[(size_t)node * 128 + (wv * 2 + nti) * 16 + m] = acc[r];
                }
            }
        }
        __syncthreads();
    }
}

extern "C" void kernel_launch(void* const* d_in, const int* in_sizes, int n_in,
                              void* d_out, int out_size, void* d_ws, size_t ws_size,
                              hipStream_t stream) {
    const float* x    = (const float*)d_in[0];
    const int*   bidx = (const int*)d_in[1];
    const float* W1  = (const float*)d_in[3];
    const float* b1  = (const float*)d_in[4];
    const float* g1  = (const float*)d_in[5];
    const float* be1 = (const float*)d_in[6];
    const float* W2  = (const float*)d_in[7];
    const float* b2  = (const float*)d_in[8];
    const float* W3  = (const float*)d_in[9];
    const float* b3  = (const float*)d_in[10];
    const float* g2  = (const float*)d_in[11];
    const float* be2 = (const float*)d_in[12];
    const float* W4  = (const float*)d_in[13];
    const float* b4  = (const float*)d_in[14];

    const int P = in_sizes[0] / 3;
    const int N = out_size / 128;
    const int nparts = (N + 255) >> 8;   // <= 256

    uintptr_t w = (uintptr_t)d_ws;
    auto align = [](uintptr_t v) { return (v + 255) & ~(uintptr_t)255; };
    unsigned* partCount = (unsigned*)align(w);      w = (uintptr_t)(partCount + 257);
    unsigned* partBase  = (unsigned*)align(w);      w = (uintptr_t)(partBase  + 257);
    unsigned* offsets   = (unsigned*)align(w);      w = (uintptr_t)(offsets   + N + 1);
    float4*   xb        = (float4*)align(w);        w = (uintptr_t)(xb        + P);
    unsigned* segord    = (unsigned*)align(w);      w = (uintptr_t)(segord    + (size_t)N * 64);
    float*    pW1e      = (float*)align(w);         w = (uintptr_t)(pW1e      + 256);
    float*    pGB       = (float*)align(w);         w = (uintptr_t)(pGB       + 128);
    float*    pSG       = (float*)align(w);         w = (uintptr_t)(pSG       + 16);
    unsigned short* pW2t = (unsigned short*)align(w); w = (uintptr_t)(pW2t + 64 * 72);
    unsigned short* W3th = (unsigned short*)align(w); w = (uintptr_t)(W3th + 128 * 64);
    unsigned short* W3tl = (unsigned short*)align(w); w = (uintptr_t)(W3tl + 128 * 64);
    unsigned short* W4th = (unsigned short*)align(w); w = (uintptr_t)(W4th + 128 * 128);
    unsigned short* W4tl = (unsigned short*)align(w); w = (uintptr_t)(W4tl + 128 * 128);
    unsigned* partCursor = (unsigned*)align(w);     w = (uintptr_t)(partCursor + 257);

    hipMemsetAsync(partCount, 0, 257 * sizeof(unsigned), stream);
    hipMemsetAsync(segord, 0, (size_t)N * 64 * sizeof(unsigned), stream);

    prep_kernel<<<1, 256, 0, stream>>>(W1, b1, g1, be1, W2, W3, W4,
                                       pW1e, pGB, pSG, pW2t, W3th, W3tl, W4th, W4tl);

    const int gridS = (P + 4095) / 4096;
    part_count_kernel<<<gridS, 256, 0, stream>>>(bidx, partCount, P);
    part_scan_kernel<<<1, 256, 0, stream>>>(partCount, partBase, partCursor, nparts);
    part_scatter_kernel<<<gridS, 256, 0, stream>>>(bidx, x, partCursor, xb, P);
    part_csr_kernel<<<nparts, 256, 0, stream>>>(partBase, offsets, xb, N);

    fused_mlp1_pool_kernel<<<(P + 255) / 256, 256, 0, stream>>>(
        xb, offsets, pW1e, pGB, pSG, pW2t, b2, segord, P);

    mlp2_mfma_kernel<<<512, 256, 0, stream>>>(
        segord, W3th, W3tl, W4th, W4tl, b3, g2, be2, b4, (float*)d_out, N);
}

// Round 8
// 377.618 us; speedup vs baseline: 15.5999x; 1.0741x over previous
//
#include <hip/hip_runtime.h>
#include <hip/hip_bf16.h>
#include <math.h>

#define EPS_LN 1e-5f

typedef __attribute__((ext_vector_type(8))) short bf16x8;
typedef __attribute__((ext_vector_type(4))) float f32x4;
typedef __attribute__((ext_vector_type(2))) unsigned short u16x2;

__device__ __forceinline__ unsigned short f2bf(float f) {
    __hip_bfloat16 h = __float2bfloat16(f);
    return *reinterpret_cast<unsigned short*>(&h);
}
__device__ __forceinline__ float bf2f(unsigned short u) {
    return __uint_as_float(((unsigned)u) << 16);
}
// monotone 16-bit key of a bf16 pattern; 0 is below all real values
__device__ __forceinline__ unsigned short ok16(float f) {
    unsigned short t = f2bf(f);
    unsigned short mask = (unsigned short)(((short)t) >> 15);
    return (unsigned short)(t ^ (unsigned short)(mask | 0x8000u));
}
// decode segord entry (key16<<16; 0 == empty -> 0.0)
__device__ __forceinline__ float decseg(unsigned o) {
    if (o == 0u) return 0.f;
    unsigned k = o >> 16;
    unsigned h = (k & 0x8000u) ? (k & 0x7FFFu) : (~k & 0xFFFFu);
    return bf2f((unsigned short)h);
}

// ---------------------------------------------------------------------------
// K0: prep — pack params once per call.
// ---------------------------------------------------------------------------
__global__ __launch_bounds__(256) void prep_kernel(
    const float* __restrict__ W1, const float* __restrict__ b1,
    const float* __restrict__ g1, const float* __restrict__ be1,
    const float* __restrict__ W2,
    const float* __restrict__ W3, const float* __restrict__ W4,
    float* __restrict__ pW1e, float* __restrict__ pGB, float* __restrict__ pSG,
    unsigned short* __restrict__ pW2t,
    unsigned short* __restrict__ W3th, unsigned short* __restrict__ W3tl,
    unsigned short* __restrict__ W4th, unsigned short* __restrict__ W4tl)
{
    const int tid = threadIdx.x;
    if (tid < 64) {
        pW1e[4 * tid + 0] = W1[tid];
        pW1e[4 * tid + 1] = W1[64 + tid];
        pW1e[4 * tid + 2] = W1[128 + tid];
        pW1e[4 * tid + 3] = b1[tid];
        pGB[2 * tid + 0] = g1[tid];
        pGB[2 * tid + 1] = be1[tid];
    }
    if (tid >= 64 && tid < 78) {
        const int t = tid - 64;
        auto wcomp = [&](int k, int i) -> float {
            return (i < 3) ? W1[i * 64 + k] : b1[k];
        };
        if (t < 4) {
            float s = 0.f;
            for (int k = 0; k < 64; k++) s += wcomp(k, t);
            pSG[t] = s;
        } else {
            const int pi[10] = {0,0,0,0,1,1,1,2,2,3};
            const int pj[10] = {0,1,2,3,1,2,3,2,3,3};
            int p = t - 4;
            float s = 0.f;
            for (int k = 0; k < 64; k++) s += wcomp(k, pi[p]) * wcomp(k, pj[p]);
            pSG[4 + p] = s;
        }
    }
    for (int i = tid; i < 4096; i += 256) {
        int k = i >> 6, n = i & 63;
        pW2t[n * 72 + k] = f2bf(W2[i]);
    }
    for (int i = tid; i < 64 * 8; i += 256) {
        int n = i >> 3, k = 64 + (i & 7);
        pW2t[n * 72 + k] = 0;
    }
    for (int i = tid; i < 8192; i += 256) {
        int k = i >> 7, n = i & 127;
        float w = W3[k * 128 + n];
        unsigned short h = f2bf(w);
        W3th[n * 64 + k] = h;
        W3tl[n * 64 + k] = f2bf(w - bf2f(h));
    }
    for (int i = tid; i < 16384; i += 256) {
        int k = i >> 7, n = i & 127;
        float w = W4[k * 128 + n];
        unsigned short h = f2bf(w);
        W4th[n * 128 + k] = h;
        W4tl[n * 128 + k] = f2bf(w - bf2f(h));
    }
}

// ---------------------------------------------------------------------------
// Sort stage 1: per-block LDS hist over 2048 partitions (node>>5),
// 4096 points/block, plain coalesced writes to blockHist[b*2048+bin].
// NO global atomics.
// ---------------------------------------------------------------------------
__global__ __launch_bounds__(256) void s1_count(const int* __restrict__ bidx,
                                                unsigned* __restrict__ blockHist, int P) {
    __shared__ unsigned hist[2048];
    const int tid = threadIdx.x;
    for (int i = tid; i < 2048; i += 256) hist[i] = 0;
    __syncthreads();
    const int base = blockIdx.x * 4096;
#pragma unroll
    for (int j = 0; j < 4; j++) {
        const int p0 = base + j * 1024 + tid * 4;
        if (p0 + 3 < P) {
            int4 n4 = *(const int4*)(bidx + p0);
            atomicAdd(&hist[((unsigned)n4.x) >> 5], 1u);
            atomicAdd(&hist[((unsigned)n4.y) >> 5], 1u);
            atomicAdd(&hist[((unsigned)n4.z) >> 5], 1u);
            atomicAdd(&hist[((unsigned)n4.w) >> 5], 1u);
        } else {
            for (int p = p0; p < P && p < p0 + 4; p++)
                atomicAdd(&hist[((unsigned)bidx[p]) >> 5], 1u);
        }
    }
    __syncthreads();
    unsigned* dst = blockHist + (size_t)blockIdx.x * 2048;
    for (int i = tid; i < 2048; i += 256) dst[i] = hist[i];
}

// ---------------------------------------------------------------------------
// Sort stage 2a: binTotal[bin] = sum over blocks. One block per bin.
// ---------------------------------------------------------------------------
__global__ __launch_bounds__(256) void s2a_total(const unsigned* __restrict__ blockHist,
                                                 unsigned* __restrict__ binTotal, int nblk) {
    const int bin = blockIdx.x;
    const int tid = threadIdx.x;
    unsigned s = 0;
    for (int b = tid; b < nblk; b += 256) s += blockHist[(size_t)b * 2048 + bin];
    for (int off = 32; off; off >>= 1) s += __shfl_down(s, off);
    __shared__ unsigned ws[4];
    if ((tid & 63) == 0) ws[tid >> 6] = s;
    __syncthreads();
    if (tid == 0) binTotal[bin] = ws[0] + ws[1] + ws[2] + ws[3];
}

// ---------------------------------------------------------------------------
// Sort stage 2b: exclusive scan of binTotal -> partBase[nparts+1]. 1 block.
// ---------------------------------------------------------------------------
__global__ __launch_bounds__(1024) void s2b_scan(const unsigned* __restrict__ binTotal,
                                                 unsigned* __restrict__ partBase,
                                                 int nparts, int P) {
    __shared__ unsigned wtot[16];
    const int t = threadIdx.x;
    const unsigned c0 = (2 * t < nparts) ? binTotal[2 * t] : 0u;
    const unsigned c1 = (2 * t + 1 < nparts) ? binTotal[2 * t + 1] : 0u;
    const unsigned s = c0 + c1;
    unsigned v = s;
    const int lane = t & 63;
    for (int off = 1; off < 64; off <<= 1) {
        unsigned u = __shfl_up(v, off);
        if (lane >= off) v += u;
    }
    if (lane == 63) wtot[t >> 6] = v;
    __syncthreads();
    if (t == 0) {
        unsigned a = 0;
        for (int w = 0; w < 16; w++) { unsigned tmp = wtot[w]; wtot[w] = a; a += tmp; }
    }
    __syncthreads();
    const unsigned excl = wtot[t >> 6] + (v - s);
    if (2 * t < nparts) partBase[2 * t] = excl;
    if (2 * t + 1 < nparts) partBase[2 * t + 1] = excl + c0;
    if (t == 0) partBase[nparts] = (unsigned)P;
}

// ---------------------------------------------------------------------------
// Sort stage 2c: per-(block,bin) cursor = partBase[bin] + excl-over-blocks,
// IN PLACE over blockHist. One block per bin; nblk <= 512.
// ---------------------------------------------------------------------------
__global__ __launch_bounds__(256) void s2c_cursor(unsigned* __restrict__ blockHist,
                                                  const unsigned* __restrict__ partBase,
                                                  int nblk) {
    __shared__ unsigned wt0[4], wb0[4], wt1[4], wb1[4], tot0s;
    const int bin = blockIdx.x;
    const int tid = threadIdx.x;
    const int lane = tid & 63;
    const unsigned c0 = (tid < nblk) ? blockHist[(size_t)tid * 2048 + bin] : 0u;
    const unsigned c1 = (tid + 256 < nblk) ? blockHist[(size_t)(tid + 256) * 2048 + bin] : 0u;

    unsigned v0 = c0;
    for (int off = 1; off < 64; off <<= 1) {
        unsigned u = __shfl_up(v0, off);
        if (lane >= off) v0 += u;
    }
    if (lane == 63) wt0[tid >> 6] = v0;
    unsigned v1 = c1;
    for (int off = 1; off < 64; off <<= 1) {
        unsigned u = __shfl_up(v1, off);
        if (lane >= off) v1 += u;
    }
    if (lane == 63) wt1[tid >> 6] = v1;
    __syncthreads();
    if (tid == 0) {
        unsigned a = 0;
        for (int i = 0; i < 4; i++) { unsigned tmp = wt0[i]; wb0[i] = a; a += tmp; }
        tot0s = a;
        a = 0;
        for (int i = 0; i < 4; i++) { unsigned tmp = wt1[i]; wb1[i] = a; a += tmp; }
    }
    __syncthreads();
    const unsigned pb = partBase[bin];
    const unsigned e0 = pb + wb0[tid >> 6] + (v0 - c0);
    const unsigned e1 = pb + tot0s + wb1[tid >> 6] + (v1 - c1);
    if (tid < nblk) blockHist[(size_t)tid * 2048 + bin] = e0;
    if (tid + 256 < nblk) blockHist[(size_t)(tid + 256) * 2048 + bin] = e1;
}

// ---------------------------------------------------------------------------
// Sort stage 3: scatter (x,node) float4 into partition-grouped xb using
// precomputed deterministic cursors (LDS-local atomics only).
// ---------------------------------------------------------------------------
__global__ __launch_bounds__(256) void s3_scatter(const int* __restrict__ bidx,
                                                  const float* __restrict__ x,
                                                  const unsigned* __restrict__ blockCursor,
                                                  float4* __restrict__ xb, int P) {
    __shared__ unsigned cur[2048];
    const int tid = threadIdx.x;
    const unsigned* src = blockCursor + (size_t)blockIdx.x * 2048;
    for (int i = tid; i < 2048; i += 256) cur[i] = src[i];
    __syncthreads();
    const int base = blockIdx.x * 4096;
#pragma unroll
    for (int j = 0; j < 4; j++) {
        const int p0 = base + j * 1024 + tid * 4;
        if (p0 + 3 < P) {
            int4 n4 = *(const int4*)(bidx + p0);
            const float4* xv = (const float4*)(x + 3 * (size_t)p0);
            float4 a = xv[0], b = xv[1], c = xv[2];
            const float xs[12] = {a.x, a.y, a.z, a.w, b.x, b.y, b.z, b.w,
                                  c.x, c.y, c.z, c.w};
            const unsigned nn[4] = {(unsigned)n4.x, (unsigned)n4.y,
                                    (unsigned)n4.z, (unsigned)n4.w};
#pragma unroll
            for (int u = 0; u < 4; u++) {
                const unsigned dst = atomicAdd(&cur[nn[u] >> 5], 1u);
                xb[dst] = make_float4(xs[3 * u], xs[3 * u + 1], xs[3 * u + 2],
                                      __uint_as_float(nn[u]));
            }
        } else {
            for (int u = 0; u < 4; u++) {
                const int p = p0 + u;
                if (p < P) {
                    const unsigned n = (unsigned)bidx[p];
                    const unsigned dst = atomicAdd(&cur[n >> 5], 1u);
                    xb[dst] = make_float4(x[3 * p], x[3 * p + 1], x[3 * p + 2],
                                          __uint_as_float(n));
                }
            }
        }
    }
}

// ---------------------------------------------------------------------------
// Sort stage 4: per-partition CSR + node-sort. One block per partition
// (~1024 recs, cap 1600 = 18 sigma). 25.6 KB LDS -> 6 blocks/CU.
// ---------------------------------------------------------------------------
__global__ __launch_bounds__(256) void s4_csr(const unsigned* __restrict__ partBase,
                                              unsigned* __restrict__ offsets,
                                              float4* __restrict__ xb, int N) {
    __shared__ float4 stage[1600];
    __shared__ unsigned hist[32], cur[32];
    const int tid = threadIdx.x;
    const int p = blockIdx.x;
    const unsigned start = partBase[p], end = partBase[p + 1];
    unsigned cnt = end - start;
    if (cnt > 1600u) cnt = 1600u;
    if (tid < 32) hist[tid] = 0;
    __syncthreads();
    for (unsigned k = tid; k < cnt; k += 256) {
        float4 r = xb[start + k];
        stage[k] = r;
        atomicAdd(&hist[__float_as_uint(r.w) & 31u], 1u);
    }
    __syncthreads();
    if (tid < 64) {
        const unsigned c = (tid < 32) ? hist[tid] : 0u;
        unsigned v = c;
        for (int off = 1; off < 32; off <<= 1) {
            unsigned u = __shfl_up(v, off);
            if (tid >= off) v += u;
        }
        if (tid < 32) {
            const unsigned excl = v - c;
            const int node = p * 32 + tid;
            if (node < N) offsets[node] = start + excl;
            cur[tid] = start + excl;
            if (node == N - 1) offsets[N] = start + excl + c;
        }
    }
    __syncthreads();
    for (unsigned k = tid; k < cnt; k += 256) {
        float4 r = stage[k];
        const unsigned dst = atomicAdd(&cur[__float_as_uint(r.w) & 31u], 1u);
        xb[dst] = r;
    }
}

// ---------------------------------------------------------------------------
// K4: fused MLP1 + chunk-segmented max pool, MFMA GEMM.
// Phase 2 stores h TRANSPOSED as ordkey16 (shbt[ch][row], stride 260,
// b64 stores). Phase 3: contiguous b64 reads + packed u16 max.
// ---------------------------------------------------------------------------
__global__ __launch_bounds__(256, 2) void fused_mlp1_pool_kernel(
    const float4* __restrict__ xb, const unsigned* __restrict__ offsets,
    const float* __restrict__ pW1e, const float* __restrict__ pGB,
    const float* __restrict__ pSG, const unsigned short* __restrict__ pW2t,
    const float* __restrict__ b2,
    unsigned* __restrict__ segord, int P)
{
    __shared__ __align__(16) unsigned short sW2t[64 * 72];   // 9.2 KB
    __shared__ __align__(16) unsigned short sa[256 * 72];    // 36 KB
    __shared__ __align__(16) unsigned short shbt[64 * 260];  // 33.3 KB, [ch][row]
    __shared__ unsigned sn01[2];

    const int tid = threadIdx.x;
    {
        const uint4* src = (const uint4*)pW2t;
        uint4* dst = (uint4*)sW2t;
        for (int i = tid; i < 576; i += 256) dst[i] = src[i];
    }

    const int base = blockIdx.x * 256;
    const int row  = tid;
    const int pos  = base + row;
    const bool valid = (pos < P);

    float x0 = 0.f, x1 = 0.f, x2 = 0.f;
    if (valid) {
        float4 v = xb[pos];
        x0 = v.x; x1 = v.y; x2 = v.z;
        unsigned node = __float_as_uint(v.w);
        if (row == 0) sn01[0] = node;
        if (row == 255 || pos == P - 1) sn01[1] = node;
    }
    __syncthreads();

    // ---- Phase 1: layer-1 + LN + ReLU via Gram trick, bf16 -> sa
    {
        const float S0 = pSG[0], S1 = pSG[1], S2 = pSG[2], S3 = pSG[3];
        const float g00 = pSG[4], g01 = pSG[5], g02 = pSG[6], g03 = pSG[7];
        const float g11 = pSG[8], g12 = pSG[9], g13 = pSG[10];
        const float g22 = pSG[11], g23 = pSG[12], g33 = pSG[13];

        const float mu = fmaf(S0, x0, fmaf(S1, x1, fmaf(S2, x2, S3))) * (1.f / 64.f);
        float q = g33;
        q = fmaf(g00, x0 * x0, q);
        q = fmaf(g11, x1 * x1, q);
        q = fmaf(g22, x2 * x2, q);
        float c = fmaf(g01, x1, fmaf(g02, x2, g03));
        q = fmaf(2.f * x0, c, q);
        q = fmaf(2.f * x1, fmaf(g12, x2, g13), q);
        q = fmaf(2.f * x2, g23, q);
        float var = q * (1.f / 64.f) - mu * mu;
        var = var > 0.f ? var : 0.f;
        const float rs = rsqrtf(var + EPS_LN);
        const float r2 = -mu * rs;

        const float4* pw = (const float4*)pW1e;
        const float2* pg = (const float2*)pGB;
#pragma unroll
        for (int kb = 0; kb < 8; kb++) {
            bf16x8 v;
#pragma unroll
            for (int u = 0; u < 8; u++) {
                const int k = kb * 8 + u;
                float4 w = pw[k];
                float2 gb = pg[k];
                float y = fmaf(x0, w.x, fmaf(x1, w.y, fmaf(x2, w.z, w.w)));
                float tn = fmaf(y, rs, r2);
                float aa = fmaf(tn, gb.x, gb.y);
                aa = aa > 0.f ? aa : 0.f;
                v[u] = (short)f2bf(aa);
            }
            *reinterpret_cast<bf16x8*>(&sa[row * 72 + kb * 8]) = v;
        }
    }
    // no barrier: each wave MFMAs only its own 64 rows.

    // ---- Phase 2: h = a @ W2 + b2 via MFMA; transposed ordkey16 store
    {
        const int wv   = tid >> 6;
        const int lane = tid & 63;
        const int m    = lane & 15;
        const int quad = lane >> 4;

        bf16x8 bfrag[4][2];
        float bc[4];
#pragma unroll
        for (int nt = 0; nt < 4; nt++) {
            bc[nt] = b2[nt * 16 + m];
#pragma unroll
            for (int s = 0; s < 2; s++)
                bfrag[nt][s] = *reinterpret_cast<const bf16x8*>(
                    &sW2t[(nt * 16 + m) * 72 + s * 32 + quad * 8]);
        }

#pragma unroll
        for (int rt = 0; rt < 4; rt++) {
            const int arow = wv * 64 + rt * 16 + m;
            bf16x8 af0 = *reinterpret_cast<const bf16x8*>(&sa[arow * 72 + quad * 8]);
            bf16x8 af1 = *reinterpret_cast<const bf16x8*>(&sa[arow * 72 + 32 + quad * 8]);
            const int orow = wv * 64 + rt * 16 + quad * 4;   // C rows this lane owns
#pragma unroll
            for (int nt = 0; nt < 4; nt++) {
                f32x4 acc = {bc[nt], bc[nt], bc[nt], bc[nt]};
                acc = __builtin_amdgcn_mfma_f32_16x16x32_bf16(af0, bfrag[nt][0], acc, 0, 0, 0);
                acc = __builtin_amdgcn_mfma_f32_16x16x32_bf16(af1, bfrag[nt][1], acc, 0, 0, 0);
                const int col = nt * 16 + m;
                uint2 pk;
                pk.x = (unsigned)ok16(acc[0]) | ((unsigned)ok16(acc[1]) << 16);
                pk.y = (unsigned)ok16(acc[2]) | ((unsigned)ok16(acc[3]) << 16);
                *reinterpret_cast<uint2*>(&shbt[col * 260 + orow]) = pk;
            }
        }
    }
    __syncthreads();

    // ---- Phase 3: segmented max, contiguous b64 reads + packed u16 max
    const int nValid = (P - base < 256) ? (P - base) : 256;
    if (nValid <= 0) return;
    const unsigned n0 = sn01[0];
    const unsigned n1 = sn01[1];
    const unsigned bEnd = (unsigned)(base + nValid);
    const int wave = tid >> 6;
    const int ch   = tid & 63;
    const unsigned short* rowp = &shbt[ch * 260];

    for (unsigned n = n0 + (unsigned)wave; n <= n1; n += 4) {
        const unsigned s = offsets[n];
        const unsigned e = offsets[n + 1];
        int lo = (int)(s > (unsigned)base ? s : (unsigned)base) - base;
        int hi = (int)(e < bEnd ? e : bEnd) - base;
        if (hi <= lo) continue;   // empty node inside range: leave 0
        u16x2 accv = {0, 0};
        unsigned short accs = 0;
        for (int r = lo & ~3; r < hi; r += 4) {
            uint2 d = *reinterpret_cast<const uint2*>(rowp + r);
            if (r >= lo && r + 4 <= hi) {
                u16x2 a = __builtin_bit_cast(u16x2, d.x);
                u16x2 b = __builtin_bit_cast(u16x2, d.y);
                accv = __builtin_elementwise_max(accv, __builtin_elementwise_max(a, b));
            } else {
                unsigned short v0 = (unsigned short)(d.x & 0xFFFFu);
                unsigned short v1 = (unsigned short)(d.x >> 16);
                unsigned short v2 = (unsigned short)(d.y & 0xFFFFu);
                unsigned short v3 = (unsigned short)(d.y >> 16);
                if (r     >= lo && r     < hi && v0 > accs) accs = v0;
                if (r + 1 >= lo && r + 1 < hi && v1 > accs) accs = v1;
                if (r + 2 >= lo && r + 2 < hi && v2 > accs) accs = v2;
                if (r + 3 >= lo && r + 3 < hi && v3 > accs) accs = v3;
            }
        }
        unsigned short k = accv.x > accv.y ? accv.x : accv.y;
        if (accs > k) k = accs;
        const unsigned key = ((unsigned)k) << 16;
        unsigned* dst = &segord[(size_t)n * 64 + ch];
        if (s >= (unsigned)base && e <= bEnd) *dst = key;   // sole writer
        else atomicMax(dst, key);                            // boundary node
    }
}

// ---------------------------------------------------------------------------
// K5: MLP2 fully in MFMA with split-bf16 (decode updated for key16 encoding).
// ---------------------------------------------------------------------------
__global__ __launch_bounds__(256) void mlp2_mfma_kernel(
    const unsigned* __restrict__ segord,
    const unsigned short* __restrict__ W3th, const unsigned short* __restrict__ W3tl,
    const unsigned short* __restrict__ W4th, const unsigned short* __restrict__ W4tl,
    const float* __restrict__ b3, const float* __restrict__ g2,
    const float* __restrict__ be2, const float* __restrict__ b4,
    float* __restrict__ out, int N)
{
    __shared__ __align__(16) unsigned short sa2[32 * 72];
    __shared__ __align__(16) float st[32 * 132];
    __shared__ __align__(16) unsigned short suh[32 * 136];
    __shared__ __align__(16) unsigned short sul[32 * 136];
    __shared__ float2 sred[32][8];
    __shared__ float sg2[128], sbe2[128];

    const int tid  = threadIdx.x;
    const int wv   = tid >> 6;
    const int lane = tid & 63;
    const int m    = lane & 15;
    const int quad = lane >> 4;

    if (tid < 128) { sg2[tid] = g2[tid]; sbe2[tid] = be2[tid]; }

    bf16x8 fw3h[2][2], fw3l[2][2];
    bf16x8 fw4h[2][4], fw4l[2][4];
    float bias3[2], bias4[2];
#pragma unroll
    for (int nti = 0; nti < 2; nti++) {
        const int nrow = (wv * 2 + nti) * 16 + m;
        bias3[nti] = b3[nrow];
        bias4[nti] = b4[nrow];
#pragma unroll
        for (int ks = 0; ks < 2; ks++) {
            fw3h[nti][ks] = *reinterpret_cast<const bf16x8*>(&W3th[nrow * 64 + ks * 32 + quad * 8]);
            fw3l[nti][ks] = *reinterpret_cast<const bf16x8*>(&W3tl[nrow * 64 + ks * 32 + quad * 8]);
        }
#pragma unroll
        for (int ks = 0; ks < 4; ks++) {
            fw4h[nti][ks] = *reinterpret_cast<const bf16x8*>(&W4th[nrow * 128 + ks * 32 + quad * 8]);
            fw4l[nti][ks] = *reinterpret_cast<const bf16x8*>(&W4tl[nrow * 128 + ks * 32 + quad * 8]);
        }
    }
    __syncthreads();

    for (int nb = blockIdx.x * 32; nb < N; nb += gridDim.x * 32) {
        {
            const int node = tid >> 3;
            const int k8   = (tid & 7) * 8;
            const uint4* sp = (const uint4*)&segord[(size_t)(nb + node) * 64 + k8];
            uint4 q0 = sp[0], q1 = sp[1];
            bf16x8 v;
            v[0] = (short)f2bf(decseg(q0.x));
            v[1] = (short)f2bf(decseg(q0.y));
            v[2] = (short)f2bf(decseg(q0.z));
            v[3] = (short)f2bf(decseg(q0.w));
            v[4] = (short)f2bf(decseg(q1.x));
            v[5] = (short)f2bf(decseg(q1.y));
            v[6] = (short)f2bf(decseg(q1.z));
            v[7] = (short)f2bf(decseg(q1.w));
            *reinterpret_cast<bf16x8*>(&sa2[node * 72 + k8]) = v;
        }
        __syncthreads();

#pragma unroll
        for (int mt = 0; mt < 2; mt++) {
            bf16x8 a0 = *reinterpret_cast<const bf16x8*>(&sa2[(mt * 16 + m) * 72 + quad * 8]);
            bf16x8 a1 = *reinterpret_cast<const bf16x8*>(&sa2[(mt * 16 + m) * 72 + 32 + quad * 8]);
#pragma unroll
            for (int nti = 0; nti < 2; nti++) {
                f32x4 acc = {bias3[nti], bias3[nti], bias3[nti], bias3[nti]};
                acc = __builtin_amdgcn_mfma_f32_16x16x32_bf16(a0, fw3h[nti][0], acc, 0, 0, 0);
                acc = __builtin_amdgcn_mfma_f32_16x16x32_bf16(a1, fw3h[nti][1], acc, 0, 0, 0);
                acc = __builtin_amdgcn_mfma_f32_16x16x32_bf16(a0, fw3l[nti][0], acc, 0, 0, 0);
                acc = __builtin_amdgcn_mfma_f32_16x16x32_bf16(a1, fw3l[nti][1], acc, 0, 0, 0);
#pragma unroll
                for (int r = 0; r < 4; r++)
                    st[(mt * 16 + quad * 4 + r) * 132 + (wv * 2 + nti) * 16 + m] = acc[r];
            }
        }
        __syncthreads();

        {
            const int node = tid >> 3;
            const int seg  = tid & 7;
            const float4* rp = (const float4*)&st[node * 132 + seg * 16];
            float4 v0 = rp[0], v1 = rp[1], v2 = rp[2], v3 = rp[3];
            float s1 = v0.x + v0.y + v0.z + v0.w + v1.x + v1.y + v1.z + v1.w
                     + v2.x + v2.y + v2.z + v2.w + v3.x + v3.y + v3.z + v3.w;
            float s2 = 0.f;
            s2 = fmaf(v0.x, v0.x, s2); s2 = fmaf(v0.y, v0.y, s2); s2 = fmaf(v0.z, v0.z, s2); s2 = fmaf(v0.w, v0.w, s2);
            s2 = fmaf(v1.x, v1.x, s2); s2 = fmaf(v1.y, v1.y, s2); s2 = fmaf(v1.z, v1.z, s2); s2 = fmaf(v1.w, v1.w, s2);
            s2 = fmaf(v2.x, v2.x, s2); s2 = fmaf(v2.y, v2.y, s2); s2 = fmaf(v2.z, v2.z, s2); s2 = fmaf(v2.w, v2.w, s2);
            s2 = fmaf(v3.x, v3.x, s2); s2 = fmaf(v3.y, v3.y, s2); s2 = fmaf(v3.z, v3.z, s2); s2 = fmaf(v3.w, v3.w, s2);
            sred[node][seg] = make_float2(s1, s2);
            __syncthreads();

            float t1 = 0.f, t2 = 0.f;
#pragma unroll
            for (int i = 0; i < 8; i++) { float2 r = sred[node][i]; t1 += r.x; t2 += r.y; }
            const float mu  = t1 * (1.f / 128.f);
            float var = t2 * (1.f / 128.f) - mu * mu;
            var = var > 0.f ? var : 0.f;
            const float rsd = rsqrtf(var + EPS_LN);

            float tv[16] = {v0.x, v0.y, v0.z, v0.w, v1.x, v1.y, v1.z, v1.w,
                            v2.x, v2.y, v2.z, v2.w, v3.x, v3.y, v3.z, v3.w};
            bf16x8 vh[2], vl[2];
#pragma unroll
            for (int i = 0; i < 16; i++) {
                const int j = seg * 16 + i;
                float u = fmaf((tv[i] - mu) * rsd, sg2[j], sbe2[j]);
                u = u > 0.f ? u : 0.f;
                unsigned short uh = f2bf(u);
                unsigned short ul = f2bf(u - bf2f(uh));
                vh[i >> 3][i & 7] = (short)uh;
                vl[i >> 3][i & 7] = (short)ul;
            }
            *reinterpret_cast<bf16x8*>(&suh[node * 136 + seg * 16])     = vh[0];
            *reinterpret_cast<bf16x8*>(&suh[node * 136 + seg * 16 + 8]) = vh[1];
            *reinterpret_cast<bf16x8*>(&sul[node * 136 + seg * 16])     = vl[0];
            *reinterpret_cast<bf16x8*>(&sul[node * 136 + seg * 16 + 8]) = vl[1];
        }
        __syncthreads();

#pragma unroll
        for (int mt = 0; mt < 2; mt++) {
            bf16x8 ah[4], al[4];
#pragma unroll
            for (int ks = 0; ks < 4; ks++) {
                ah[ks] = *reinterpret_cast<const bf16x8*>(&suh[(mt * 16 + m) * 136 + ks * 32 + quad * 8]);
                al[ks] = *reinterpret_cast<const bf16x8*>(&sul[(mt * 16 + m) * 136 + ks * 32 + quad * 8]);
            }
#pragma unroll
            for (int nti = 0; nti < 2; nti++) {
                f32x4 acc = {bias4[nti], bias4[nti], bias4[nti], bias4[nti]};
#pragma unroll
                for (int ks = 0; ks < 4; ks++) {
                    acc = __builtin_amdgcn_mfma_f32_16x16x32_bf16(ah[ks], fw4h[nti][ks], acc, 0, 0, 0);
                    acc = __builtin_amdgcn_mfma_f32_16x16x32_bf16(al[ks], fw4h[nti][ks], acc, 0, 0, 0);
                    acc = __builtin_amdgcn_mfma_f32_16x16x32_bf16(ah[ks], fw4l[nti][ks], acc, 0, 0, 0);
                }
#pragma unroll
                for (int r = 0; r < 4; r++) {
                    const int node = nb + mt * 16 + quad * 4 + r;
                    if (node < N)
                        out[(size_t)node * 128 + (wv * 2 + nti) * 16 + m] = acc[r];
                }
            }
        }
        __syncthreads();
    }
}

extern "C" void kernel_launch(void* const* d_in, const int* in_sizes, int n_in,
                              void* d_out, int out_size, void* d_ws, size_t ws_size,
                              hipStream_t stream) {
    const float* x    = (const float*)d_in[0];
    const int*   bidx = (const int*)d_in[1];
    const float* W1  = (const float*)d_in[3];
    const float* b1  = (const float*)d_in[4];
    const float* g1  = (const float*)d_in[5];
    const float* be1 = (const float*)d_in[6];
    const float* W2  = (const float*)d_in[7];
    const float* b2  = (const float*)d_in[8];
    const float* W3  = (const float*)d_in[9];
    const float* b3  = (const float*)d_in[10];
    const float* g2  = (const float*)d_in[11];
    const float* be2 = (const float*)d_in[12];
    const float* W4  = (const float*)d_in[13];
    const float* b4  = (const float*)d_in[14];

    const int P = in_sizes[0] / 3;
    const int N = out_size / 128;
    const int nparts = (N + 31) >> 5;          // <= 2048
    const int nblk   = (P + 4095) / 4096;      // <= 512

    uintptr_t w = (uintptr_t)d_ws;
    auto align = [](uintptr_t v) { return (v + 255) & ~(uintptr_t)255; };
    unsigned* blockHist = (unsigned*)align(w);     w = (uintptr_t)(blockHist + (size_t)nblk * 2048);
    unsigned* binTotal  = (unsigned*)align(w);     w = (uintptr_t)(binTotal  + 2048);
    unsigned* partBase  = (unsigned*)align(w);     w = (uintptr_t)(partBase  + 2049);
    unsigned* offsets   = (unsigned*)align(w);     w = (uintptr_t)(offsets   + N + 1);
    float4*   xb        = (float4*)align(w);       w = (uintptr_t)(xb        + P);
    unsigned* segord    = (unsigned*)align(w);     w = (uintptr_t)(segord    + (size_t)N * 64);
    float*    pW1e      = (float*)align(w);        w = (uintptr_t)(pW1e      + 256);
    float*    pGB       = (float*)align(w);        w = (uintptr_t)(pGB       + 128);
    float*    pSG       = (float*)align(w);        w = (uintptr_t)(pSG       + 16);
    unsigned short* pW2t = (unsigned short*)align(w); w = (uintptr_t)(pW2t + 64 * 72);
    unsigned short* W3th = (unsigned short*)align(w); w = (uintptr_t)(W3th + 128 * 64);
    unsigned short* W3tl = (unsigned short*)align(w); w = (uintptr_t)(W3tl + 128 * 64);
    unsigned short* W4th = (unsigned short*)align(w); w = (uintptr_t)(W4th + 128 * 128);
    unsigned short* W4tl = (unsigned short*)align(w); w = (uintptr_t)(W4tl + 128 * 128);

    hipMemsetAsync(segord, 0, (size_t)N * 64 * sizeof(unsigned), stream);

    prep_kernel<<<1, 256, 0, stream>>>(W1, b1, g1, be1, W2, W3, W4,
                                       pW1e, pGB, pSG, pW2t, W3th, W3tl, W4th, W4tl);

    s1_count<<<nblk, 256, 0, stream>>>(bidx, blockHist, P);
    s2a_total<<<nparts, 256, 0, stream>>>(blockHist, binTotal, nblk);
    s2b_scan<<<1, 1024, 0, stream>>>(binTotal, partBase, nparts, P);
    s2c_cursor<<<nparts, 256, 0, stream>>>(blockHist, partBase, nblk);
    s3_scatter<<<nblk, 256, 0, stream>>>(bidx, x, blockHist, xb, P);
    s4_csr<<<nparts, 256, 0, stream>>>(partBase, offsets, xb, N);

    fused_mlp1_pool_kernel<<<(P + 255) / 256, 256, 0, stream>>>(
        xb, offsets, pW1e, pGB, pSG, pW2t, b2, segord, P);

    mlp2_mfma_kernel<<<512, 256, 0, stream>>>(
        segord, W3th, W3tl, W4th, W4tl, b3, g2, be2, b4, (float*)d_out, N);
}